// Round 11
// baseline (2586.119 us; speedup 1.0000x reference)
//
#include <hip/hip_runtime.h>
#include <math.h>

#define BB 16
#define LL 4096
#define DIN 8
#define DD 512
#define HH 8
#define DKK 64
#define DFF 2048
#define OUTLEN 96
#define TAIL0 (LL - OUTLEN)   /* 4000 */
#define NTAIL (BB * OUTLEN)   /* 1536 */
#define UMAX 10
#define CH 8192               /* FFN row chunk */
#define QKVN 1536
#define NB 4                  /* batches per quarter */
#define QM (NB * LL)          /* 16384 rows per quarter */
#define NSPLIT 32
#define LCHUNK (LL / NSPLIT)  /* 128 */
#define PSTRIDE 68
#define MAXSLOT 128
#define EROWS 16

typedef unsigned short ushort_t;
typedef unsigned int uint_t;
typedef short bf16x8 __attribute__((ext_vector_type(8)));
typedef float f32x4 __attribute__((ext_vector_type(4)));

#define GLD16(gp, lp) __builtin_amdgcn_global_load_lds((const __attribute__((address_space(1))) void*)(gp), (__attribute__((address_space(3))) void*)(lp), 16, 0, 0)

// ---------- helpers ----------
__device__ inline float wsum(float v){
#pragma unroll
  for (int o = 32; o > 0; o >>= 1) v += __shfl_xor(v, o);
  return v;
}
__device__ inline ushort_t f2bf_rtn(float f){
  uint_t u = __float_as_uint(f);
  uint_t r = u + 0x7FFF + ((u >> 16) & 1);
  return (ushort_t)(r >> 16);
}
__device__ inline float bf2f(ushort_t u){
  return __uint_as_float(((uint_t)u) << 16);
}
__device__ inline void split2(float x, ushort_t& hi, ushort_t& lo){
  uint_t u = __float_as_uint(x);
  hi = (ushort_t)(u >> 16);
  lo = f2bf_rtn(x - __uint_as_float(u & 0xFFFF0000u));
}
// bijective XCD-chunked swizzle (m204)
__device__ inline void xcd_map(int& bx, int& by){
  const int gx = gridDim.x;
  const int nwg = gx * gridDim.y;
  const int wg = (int)blockIdx.y * gx + (int)blockIdx.x;
  const int q = nwg >> 3, r = nwg & 7;
  const int xcd = wg & 7, idx = wg >> 3;
  const int swz = (xcd < r ? xcd * (q + 1) : r * (q + 1) + (xcd - r) * q) + idx;
  bx = swz % gx; by = swz / gx;
}

// ---------- embed: 16 rows/block, packed stores ----------
__global__ __launch_bounds__(256) void embed_kernel(const float* __restrict__ x,
    const float* __restrict__ we, const float* __restrict__ be,
    ushort_t* __restrict__ hh, ushort_t* __restrict__ hl){
  const int row0 = blockIdx.x * EROWS;
  __shared__ float xs[EROWS][DIN];
  const int t = threadIdx.x;
  if (t < EROWS * DIN) xs[t >> 3][t & 7] = x[(size_t)row0 * DIN + t];
  __syncthreads();
  const int j0 = 2 * t;
  float w0[DIN], w1r[DIN];
#pragma unroll
  for (int i = 0; i < DIN; ++i){ w0[i] = we[i * DD + j0]; w1r[i] = we[i * DD + j0 + 1]; }
  const float b0 = be[j0], b1 = be[j0 + 1];
#pragma unroll
  for (int rr = 0; rr < EROWS; ++rr){
    float a0 = b0, a1 = b1;
#pragma unroll
    for (int i = 0; i < DIN; ++i){ a0 += xs[rr][i] * w0[i]; a1 += xs[rr][i] * w1r[i]; }
    ushort_t h0, l0, h1, l1;
    split2(a0, h0, l0); split2(a1, h1, l1);
    ((uint_t*)(hh + (size_t)(row0 + rr) * DD))[t] = (uint_t)h0 | ((uint_t)h1 << 16);
    ((uint_t*)(hl + (size_t)(row0 + rr) * DD))[t] = (uint_t)l0 | ((uint_t)l1 << 16);
  }
}

// ---------- weight prep: LDS 32x32 tile transpose ----------
__global__ __launch_bounds__(256) void wsplit_t_kernel(const float* __restrict__ W,
    ushort_t* __restrict__ Th, ushort_t* __restrict__ Tl, int K, int N){
  __shared__ float tile[32][33];
  const int n0 = blockIdx.x * 32;
  const int k0 = blockIdx.y * 32;
  const int tr = threadIdx.x >> 5;
  const int tc = threadIdx.x & 31;
#pragma unroll
  for (int rr = 0; rr < 4; ++rr)
    tile[tr + rr * 8][tc] = W[(size_t)(k0 + tr + rr * 8) * N + n0 + tc];
  __syncthreads();
#pragma unroll
  for (int rr = 0; rr < 4; ++rr){
    const int n = n0 + tr + rr * 8;
    ushort_t hi, lo;
    split2(tile[tc][tr + rr * 8], hi, lo);
    Th[(size_t)n * K + k0 + tc] = hi;
    Tl[(size_t)n * K + k0 + tc] = lo;
  }
}
__global__ __launch_bounds__(256) void wqkv_prep_kernel(const float* __restrict__ wq,
    const float* __restrict__ wk, const float* __restrict__ wv,
    ushort_t* __restrict__ Th, ushort_t* __restrict__ Tl){
  __shared__ float tile[32][33];
  const int n0 = blockIdx.x * 32;
  const int k0 = blockIdx.y * 32;
  const float* src = (n0 < 512) ? wq : (n0 < 1024) ? wk : wv;
  const int nb = n0 & 511;
  const int tr = threadIdx.x >> 5;
  const int tc = threadIdx.x & 31;
#pragma unroll
  for (int rr = 0; rr < 4; ++rr)
    tile[tr + rr * 8][tc] = src[(size_t)(k0 + tr + rr * 8) * DD + nb + tc];
  __syncthreads();
#pragma unroll
  for (int rr = 0; rr < 4; ++rr){
    const int n = n0 + tr + rr * 8;
    ushort_t hi, lo;
    split2(tile[tc][tr + rr * 8], hi, lo);
    Th[(size_t)n * DD + k0 + tc] = hi;
    Tl[(size_t)n * DD + k0 + tc] = lo;
  }
}
__global__ __launch_bounds__(256) void bqkv_prep_kernel(const float* __restrict__ bq,
    const float* __restrict__ bk, const float* __restrict__ bv, float* __restrict__ bo_){
  int n = blockIdx.x * 256 + threadIdx.x;
  if (n >= QKVN) return;
  bo_[n] = (n < 512) ? bq[n] : (n < 1024) ? bk[n - 512] : bv[n - 1024];
}

// ---------- QKV GEMM + fused qs scoring ----------
// Each Q-wave covers 64 rows x one head (64 cols): qs stats computed from
// accumulators via 16-lane shfl reduces, written straight to qsb.
__global__ __launch_bounds__(256) void gemm_qkv(
    const ushort_t* __restrict__ Ah, const ushort_t* __restrict__ Al,
    const ushort_t* __restrict__ Bh, const ushort_t* __restrict__ Bl,
    const float* __restrict__ bias, float* __restrict__ Q,
    ushort_t* __restrict__ KV, float* __restrict__ qsb){
  __shared__ __align__(16) ushort_t AsH[128 * 32];
  __shared__ __align__(16) ushort_t AsL[128 * 32];
  __shared__ __align__(16) ushort_t BsH[128 * 32];
  __shared__ __align__(16) ushort_t BsL[128 * 32];
  int bx, by; xcd_map(bx, by);
  const int tid  = threadIdx.x;
  const int lane = tid & 63;
  const int wv   = tid >> 6;
  const int m0   = by * 128;
  const int n0   = bx * 128;
  const bool isQ = (n0 < 512);
  const int wm   = (wv & 1) * 64;
  const int wn   = (wv >> 1) * 64;

  const int rowA = tid >> 2;
  const int qe   = (tid & 3) * 8;
  const int lds0 = tid * 8;
  const int lds1 = (tid + 256) * 8;

  f32x4 acc[4][4];
#pragma unroll
  for (int i = 0; i < 4; ++i)
#pragma unroll
    for (int j = 0; j < 4; ++j) acc[i][j] = (f32x4){0.f, 0.f, 0.f, 0.f};

  const int arow = lane & 15;
  const int koff = (lane >> 4) * 8;
  const int K = DD;

  for (int k0 = 0; k0 < K; k0 += 32){
    const size_t ga0 = (size_t)(m0 + rowA) * K + k0 + qe;
    const size_t ga1 = (size_t)(m0 + rowA + 64) * K + k0 + qe;
    const size_t gb0 = (size_t)(n0 + rowA) * K + k0 + qe;
    const size_t gb1 = (size_t)(n0 + rowA + 64) * K + k0 + qe;
    GLD16(Ah + ga0, &AsH[lds0]);  GLD16(Ah + ga1, &AsH[lds1]);
    GLD16(Al + ga0, &AsL[lds0]);  GLD16(Al + ga1, &AsL[lds1]);
    GLD16(Bh + gb0, &BsH[lds0]);  GLD16(Bh + gb1, &BsH[lds1]);
    if (isQ){ GLD16(Bl + gb0, &BsL[lds0]);  GLD16(Bl + gb1, &BsL[lds1]); }
    __syncthreads();

    bf16x8 ah[4], al[4], bh[4], bl[4];
#pragma unroll
    for (int i = 0; i < 4; ++i){
      ah[i] = *(const bf16x8*)&AsH[(wm + i * 16 + arow) * 32 + koff];
      al[i] = *(const bf16x8*)&AsL[(wm + i * 16 + arow) * 32 + koff];
      bh[i] = *(const bf16x8*)&BsH[(wn + i * 16 + arow) * 32 + koff];
      if (isQ) bl[i] = *(const bf16x8*)&BsL[(wn + i * 16 + arow) * 32 + koff];
    }
#pragma unroll
    for (int i = 0; i < 4; ++i)
#pragma unroll
      for (int j = 0; j < 4; ++j){
        acc[i][j] = __builtin_amdgcn_mfma_f32_16x16x32_bf16(ah[i], bh[j], acc[i][j], 0, 0, 0);
        acc[i][j] = __builtin_amdgcn_mfma_f32_16x16x32_bf16(al[i], bh[j], acc[i][j], 0, 0, 0);
        if (isQ)
          acc[i][j] = __builtin_amdgcn_mfma_f32_16x16x32_bf16(ah[i], bl[j], acc[i][j], 0, 0, 0);
      }
    __syncthreads();
  }

  const int crow = (lane >> 4) * 4;
  const int ccol = lane & 15;
#pragma unroll
  for (int i = 0; i < 4; ++i){
    const int gr0 = m0 + wm + i * 16 + crow;
#pragma unroll
    for (int j = 0; j < 4; ++j){
      const int gc = n0 + wn + j * 16 + ccol;
      const float bvv = bias[gc];
#pragma unroll
      for (int r = 0; r < 4; ++r){
        float v = acc[i][j][r] + bvv;
        const int gr = gr0 + r;
        if (isQ) Q[(size_t)gr * 512 + gc] = v;
        else     KV[(size_t)gr * 1024 + (gc - 512)] = f2bf_rtn(v);
      }
    }
  }

  if (isQ){
    // fused qs scoring: wave covers head hhd, rows wm..wm+63 of this 128-row tile
    const int hhd = (n0 >> 6) + (wn >> 6);
    const int grp = lane >> 4;
    const int lid = lane & 15;
#pragma unroll
    for (int i = 0; i < 4; ++i){
#pragma unroll
      for (int r = 0; r < 4; ++r){
        float v0a = acc[i][0][r] + bias[n0 + wn + 0  + lid];
        float v1a = acc[i][1][r] + bias[n0 + wn + 16 + lid];
        float v2a = acc[i][2][r] + bias[n0 + wn + 32 + lid];
        float v3a = acc[i][3][r] + bias[n0 + wn + 48 + lid];
        float s1 = v0a + v1a + v2a + v3a;
        float s2 = v0a*v0a + v1a*v1a + v2a*v2a + v3a*v3a;
        float mx = fmaxf(fmaxf(v0a, v1a), fmaxf(v2a, v3a));
#pragma unroll
        for (int o2 = 8; o2 > 0; o2 >>= 1){
          s1 += __shfl_xor(s1, o2);
          s2 += __shfl_xor(s2, o2);
          mx = fmaxf(mx, __shfl_xor(mx, o2));
        }
        float e0 = expf(v0a - mx), e1 = expf(v1a - mx);
        float e2 = expf(v2a - mx), e3 = expf(v3a - mx);
        float se = e0 + e1 + e2 + e3;
#pragma unroll
        for (int o2 = 8; o2 > 0; o2 >>= 1) se += __shfl_xor(se, o2);
        float inv = 1.0f / se;
        float p0 = e0*inv, p1 = e1*inv, p2 = e2*inv, p3 = e3*inv;
        float en = p0*logf(p0+1e-9f) + p1*logf(p1+1e-9f)
                 + p2*logf(p2+1e-9f) + p3*logf(p3+1e-9f);
#pragma unroll
        for (int o2 = 8; o2 > 0; o2 >>= 1) en += __shfl_xor(en, o2);
        float ent = -en;
        float l2n = sqrtf(s2);
        float mu  = s1 * (1.0f / 64.0f);
        float var = (s2 - 64.0f * mu * mu) * (1.0f / 63.0f);
        float val = 0.5f * l2n + 0.3f * ent + 0.2f * var;
        if (lid == 0){
          const int gr = m0 + wm + i * 16 + grp * 4 + r;
          const int bloc = gr >> 12, l = gr & (LL - 1);
          qsb[(size_t)(bloc * HH + hhd) * LL + l] = val;
        }
      }
    }
  }
}

// ---------- FFN1: A split bf16, B=w1 hi only (x2), out = relu bf16 ----------
__global__ __launch_bounds__(256) void gemm_ffn1(
    const ushort_t* __restrict__ Ah, const ushort_t* __restrict__ Al,
    const ushort_t* __restrict__ Bh, const float* __restrict__ bias,
    ushort_t* __restrict__ Chid){
  __shared__ __align__(16) ushort_t AsH[128 * 32];
  __shared__ __align__(16) ushort_t AsL[128 * 32];
  __shared__ __align__(16) ushort_t BsH[128 * 32];
  int bx, by; xcd_map(bx, by);
  const int tid  = threadIdx.x;
  const int lane = tid & 63;
  const int wv   = tid >> 6;
  const int m0   = by * 128;
  const int n0   = bx * 128;
  const int wm   = (wv & 1) * 64;
  const int wn   = (wv >> 1) * 64;
  const int rowA = tid >> 2;
  const int qe   = (tid & 3) * 8;
  const int lds0 = tid * 8;
  const int lds1 = (tid + 256) * 8;

  f32x4 acc[4][4];
#pragma unroll
  for (int i = 0; i < 4; ++i)
#pragma unroll
    for (int j = 0; j < 4; ++j) acc[i][j] = (f32x4){0.f, 0.f, 0.f, 0.f};

  const int arow = lane & 15;
  const int koff = (lane >> 4) * 8;
  const int K = DD;

  for (int k0 = 0; k0 < K; k0 += 32){
    const size_t ga0 = (size_t)(m0 + rowA) * K + k0 + qe;
    const size_t ga1 = (size_t)(m0 + rowA + 64) * K + k0 + qe;
    const size_t gb0 = (size_t)(n0 + rowA) * K + k0 + qe;
    const size_t gb1 = (size_t)(n0 + rowA + 64) * K + k0 + qe;
    GLD16(Ah + ga0, &AsH[lds0]);  GLD16(Ah + ga1, &AsH[lds1]);
    GLD16(Al + ga0, &AsL[lds0]);  GLD16(Al + ga1, &AsL[lds1]);
    GLD16(Bh + gb0, &BsH[lds0]);  GLD16(Bh + gb1, &BsH[lds1]);
    __syncthreads();

    bf16x8 ah[4], al[4], bh[4];
#pragma unroll
    for (int i = 0; i < 4; ++i){
      ah[i] = *(const bf16x8*)&AsH[(wm + i * 16 + arow) * 32 + koff];
      al[i] = *(const bf16x8*)&AsL[(wm + i * 16 + arow) * 32 + koff];
      bh[i] = *(const bf16x8*)&BsH[(wn + i * 16 + arow) * 32 + koff];
    }
#pragma unroll
    for (int i = 0; i < 4; ++i)
#pragma unroll
      for (int j = 0; j < 4; ++j){
        acc[i][j] = __builtin_amdgcn_mfma_f32_16x16x32_bf16(ah[i], bh[j], acc[i][j], 0, 0, 0);
        acc[i][j] = __builtin_amdgcn_mfma_f32_16x16x32_bf16(al[i], bh[j], acc[i][j], 0, 0, 0);
      }
    __syncthreads();
  }

  const int crow = (lane >> 4) * 4;
  const int ccol = lane & 15;
#pragma unroll
  for (int i = 0; i < 4; ++i){
    const int gr0 = m0 + wm + i * 16 + crow;
#pragma unroll
    for (int j = 0; j < 4; ++j){
      const int gc = n0 + wn + j * 16 + ccol;
      const float bvv = bias[gc];
#pragma unroll
      for (int r = 0; r < 4; ++r){
        float v = fmaxf(acc[i][j][r] + bvv, 0.f);
        Chid[(size_t)(gr0 + r) * DFF + gc] = f2bf_rtn(v);
      }
    }
  }
}

// ---------- FFN2: A single bf16 (hid), B=w2 split (x2), split-K=2 partial fp32 out ----------
__global__ __launch_bounds__(256) void gemm_ffn2(
    const ushort_t* __restrict__ Ahid,
    const ushort_t* __restrict__ Bh, const ushort_t* __restrict__ Bl,
    float* __restrict__ pbuf, size_t pstr){
  __shared__ __align__(16) ushort_t AsH[128 * 32];
  __shared__ __align__(16) ushort_t BsH[128 * 32];
  __shared__ __align__(16) ushort_t BsL[128 * 32];
  int bx, by; xcd_map(bx, by);
  const int tid  = threadIdx.x;
  const int lane = tid & 63;
  const int wv   = tid >> 6;
  const int nblk = bx >> 1;
  const int kq   = bx & 1;
  const int m0   = by * 128;
  const int n0   = nblk * 128;
  const int wm   = (wv & 1) * 64;
  const int wn   = (wv >> 1) * 64;
  const int rowA = tid >> 2;
  const int qe   = (tid & 3) * 8;
  const int lds0 = tid * 8;
  const int lds1 = (tid + 256) * 8;

  f32x4 acc[4][4];
#pragma unroll
  for (int i = 0; i < 4; ++i)
#pragma unroll
    for (int j = 0; j < 4; ++j) acc[i][j] = (f32x4){0.f, 0.f, 0.f, 0.f};

  const int arow = lane & 15;
  const int koff = (lane >> 4) * 8;
  const int K = DFF;
  const int kper = K / 2;
  const int kbeg = kq * kper;

  for (int k0 = kbeg; k0 < kbeg + kper; k0 += 32){
    const size_t ga0 = (size_t)(m0 + rowA) * K + k0 + qe;
    const size_t ga1 = (size_t)(m0 + rowA + 64) * K + k0 + qe;
    const size_t gb0 = (size_t)(n0 + rowA) * K + k0 + qe;
    const size_t gb1 = (size_t)(n0 + rowA + 64) * K + k0 + qe;
    GLD16(Ahid + ga0, &AsH[lds0]);  GLD16(Ahid + ga1, &AsH[lds1]);
    GLD16(Bh + gb0, &BsH[lds0]);    GLD16(Bh + gb1, &BsH[lds1]);
    GLD16(Bl + gb0, &BsL[lds0]);    GLD16(Bl + gb1, &BsL[lds1]);
    __syncthreads();

    bf16x8 ah[4], bh[4], bl[4];
#pragma unroll
    for (int i = 0; i < 4; ++i){
      ah[i] = *(const bf16x8*)&AsH[(wm + i * 16 + arow) * 32 + koff];
      bh[i] = *(const bf16x8*)&BsH[(wn + i * 16 + arow) * 32 + koff];
      bl[i] = *(const bf16x8*)&BsL[(wn + i * 16 + arow) * 32 + koff];
    }
#pragma unroll
    for (int i = 0; i < 4; ++i)
#pragma unroll
      for (int j = 0; j < 4; ++j){
        acc[i][j] = __builtin_amdgcn_mfma_f32_16x16x32_bf16(ah[i], bh[j], acc[i][j], 0, 0, 0);
        acc[i][j] = __builtin_amdgcn_mfma_f32_16x16x32_bf16(ah[i], bl[j], acc[i][j], 0, 0, 0);
      }
    __syncthreads();
  }

  const int crow = (lane >> 4) * 4;
  const int ccol = lane & 15;
#pragma unroll
  for (int i = 0; i < 4; ++i){
    const int gr0 = m0 + wm + i * 16 + crow;
#pragma unroll
    for (int j = 0; j < 4; ++j){
      const int gc = n0 + wn + j * 16 + ccol;
#pragma unroll
      for (int r = 0; r < 4; ++r)
        pbuf[(size_t)kq * pstr + (size_t)(gr0 + r) * DD + gc] = acc[i][j][r];
    }
  }
}

// ---------- selection (incremental top-k) + fused slot allocation ----------
__global__ __launch_bounds__(256) void select_kernel(const float* __restrict__ qsb,
    int* __restrict__ topidx, int* __restrict__ ufac,
    int* __restrict__ slotmap, int* __restrict__ scount, int qtr){
  __shared__ float vals[LL];
  __shared__ float bv[256];
  __shared__ int   bi[256];
  __shared__ int   widx_s;
  __shared__ int   swin[UMAX];
  __shared__ double r1[256], r2[256];
  const int bloc = blockIdx.y;
  const int b = qtr * NB + bloc;
  int tid = threadIdx.x;
  if (blockIdx.x == 8){
    const float* row = qsb + (size_t)bloc * HH * LL;
    double s = 0.0, s2 = 0.0;
    for (int l = tid; l < LL; l += 256){ double v = row[l]; s += v; s2 += v * v; }
    r1[tid] = s; r2[tid] = s2; __syncthreads();
    for (int st = 128; st; st >>= 1){
      if (tid < st){ r1[tid] += r1[tid+st]; r2[tid] += r2[tid+st]; }
      __syncthreads();
    }
    if (tid == 0){
      double mean = r1[0] / (double)LL;
      double var  = (r2[0] - (double)LL * mean * mean) / (double)(LL - 1);
      if (var < 0.0) var = 0.0;
      double f = rint(sqrt(var) / (mean + 1e-6) * 10.0);
      if (f < 3.0) f = 3.0;
      if (f > 10.0) f = 10.0;
      ufac[b] = (int)f;
    }
    return;
  }
  int hh = blockIdx.x;
  const float* row = qsb + ((size_t)bloc * HH + hh) * LL;
  for (int l = tid; l < LL; l += 256) vals[l] = row[l];
  __syncthreads();
  float lmax = -INFINITY; int lidx = 0;
  for (int l = tid; l < LL; l += 256){
    float v = vals[l];
    if (v > lmax){ lmax = v; lidx = l; }
  }
  for (int it = 0; it < UMAX; ++it){
    bv[tid] = lmax; bi[tid] = lidx;
    __syncthreads();
    for (int st = 128; st; st >>= 1){
      if (tid < st){
        if (bv[tid+st] > bv[tid] || (bv[tid+st] == bv[tid] && bi[tid+st] < bi[tid])){
          bv[tid] = bv[tid+st]; bi[tid] = bi[tid+st];
        }
      }
      __syncthreads();
    }
    if (tid == 0){ topidx[(b * HH + hh) * UMAX + it] = bi[0]; widx_s = bi[0]; swin[it] = bi[0]; }
    __syncthreads();
    const int w = widx_s;
    if ((w & 255) == tid){
      vals[w] = -INFINITY;
      lmax = -INFINITY; lidx = 0;
      for (int l = tid; l < LL; l += 256){
        float v = vals[l];
        if (v > lmax){ lmax = v; lidx = l; }
      }
    }
    __syncthreads();
  }
  // fused slot allocation (allocating for rank>=u is harmless: adelta stays 0 there)
  if (tid < UMAX){
    int qpos = swin[tid];
    int* cell = &slotmap[b * LL + qpos];
    int old = atomicCAS(cell, -1, -2);
    if (old == -1){
      int s = atomicAdd(&scount[b], 1);
      atomicExch(cell, s);
    }
  }
}

// ---------- reset: slotmap=-1, scount=0, adelta=0 ----------
__global__ void reset_kernel(int* __restrict__ slotmap, int* __restrict__ scount,
    float* __restrict__ adelta){
  size_t i = (size_t)blockIdx.x * 256 + threadIdx.x;
  size_t stride = (size_t)gridDim.x * 256;
  for (size_t k = i; k < (size_t)BB * LL; k += stride) slotmap[k] = -1;
  for (size_t k = i; k < (size_t)BB * MAXSLOT * DD; k += stride) adelta[k] = 0.f;
  if (i < BB) scount[i] = 0;
}

// ---------- attention pass 1: K/V in regs once, loop over ranks ----------
__global__ __launch_bounds__(256) void attn_p1_kernel(const float* __restrict__ qbuf,
    const ushort_t* __restrict__ kvbuf,
    const int* __restrict__ topidx, const int* __restrict__ ufac,
    float* __restrict__ part, int qtr, int lmin){
  const int bloc = blockIdx.z;
  const int b = qtr * NB + bloc;
  const int hh = blockIdx.y;
  const int u = ufac[b];
  const int tid = threadIdx.x, lane = tid & 63, wv = tid >> 6;
  const int base = blockIdx.x * LCHUNK + wv * 32;

  const ushort_t* Kp = kvbuf + (size_t)bloc * LL * 1024 + hh * DKK + lane;
  const ushort_t* Vp = Kp + 512;
  float kreg[32], vreg[32];
#pragma unroll
  for (int i = 0; i < 32; ++i){
    kreg[i] = bf2f(Kp[(size_t)(base + i) * 1024]);
    vreg[i] = bf2f(Vp[(size_t)(base + i) * 1024]);
  }

  __shared__ float wm4[4], ws4[4];
  __shared__ float pvs[4][DKK];

  for (int rank = 0; rank < u; ++rank){
    const int qpos = topidx[(b * HH + hh) * UMAX + rank];
    if (qpos < lmin) continue;
    const float qv = qbuf[((size_t)bloc * LL + qpos) * DD + hh * DKK + lane];

    float sc[32];
    float mloc = -INFINITY;
#pragma unroll
    for (int i = 0; i < 32; ++i){
      float s = wsum(qv * kreg[i]) * 0.125f;
      sc[i] = s;
      mloc = fmaxf(mloc, s);
    }
    if (lane == 0) wm4[wv] = mloc;
    __syncthreads();
    const float M4 = fmaxf(fmaxf(wm4[0], wm4[1]), fmaxf(wm4[2], wm4[3]));

    float ssum = 0.f;
#pragma unroll
    for (int i = 0; i < 32; ++i){ float e = expf(sc[i] - M4); sc[i] = e; ssum += e; }

    float pv = 0.f;
#pragma unroll
    for (int i = 0; i < 32; ++i) pv += sc[i] * vreg[i];

    pvs[wv][lane] = pv;
    if (lane == 0) ws4[wv] = ssum;
    __syncthreads();
    if (wv == 0){
      const int rowid = hh * UMAX + rank;
      float* rec = part + (size_t)((bloc * HH * UMAX + rowid) * NSPLIT + blockIdx.x) * PSTRIDE;
      rec[lane] = pvs[0][lane] + pvs[1][lane] + pvs[2][lane] + pvs[3][lane];
      if (lane == 0){ rec[64] = M4; rec[65] = ws4[0] + ws4[1] + ws4[2] + ws4[3]; }
    }
    __syncthreads();
  }
}

// ---------- attention pass 2: combine + wo projection -> adelta ----------
__global__ __launch_bounds__(256) void attn_p2_kernel(const float* __restrict__ part,
    const float* __restrict__ wo, const int* __restrict__ topidx, const int* __restrict__ ufac,
    const int* __restrict__ slotmap, float* __restrict__ adelta, int qtr, int lmin){
  const int bloc = blockIdx.y;
  const int b = qtr * NB + bloc;
  const int rowid = blockIdx.x;
  const int hh = rowid / UMAX, rank = rowid % UMAX;
  if (rank >= ufac[b]) return;
  const int qpos = topidx[(b * HH + hh) * UMAX + rank];
  if (qpos < lmin) return;
  const int slot = slotmap[b * LL + qpos];

  const int tid = threadIdx.x;
  const float* pbase = part + (size_t)(bloc * HH * UMAX + rowid) * NSPLIT * PSTRIDE;
  __shared__ float pm[NSPLIT], ps[NSPLIT];
  __shared__ float orow[DKK];
  if (tid < NSPLIT){
    pm[tid] = pbase[(size_t)tid * PSTRIDE + 64];
    ps[tid] = pbase[(size_t)tid * PSTRIDE + 65];
  }
  __syncthreads();
  float M = -INFINITY;
#pragma unroll
  for (int i = 0; i < NSPLIT; ++i) M = fmaxf(M, pm[i]);
  float S = 0.f;
#pragma unroll
  for (int i = 0; i < NSPLIT; ++i) S += ps[i] * expf(pm[i] - M);
  if (tid < DKK){
    float acc = 0.f;
#pragma unroll
    for (int i = 0; i < NSPLIT; ++i)
      acc += pbase[(size_t)i * PSTRIDE + tid] * expf(pm[i] - M);
    orow[tid] = acc / S;
  }
  __syncthreads();
  float* drow = adelta + ((size_t)b * MAXSLOT + slot) * DD;
  for (int j = tid; j < DD; j += 256){
    float a = 0.f;
#pragma unroll
    for (int dd = 0; dd < DKK; ++dd) a += orow[dd] * wo[(size_t)(hh * DKK + dd) * DD + j];
    atomicAdd(&drow[j], a);
  }
}

// ---------- LN1: one-pass sum/sumsq, wave reduce ----------
template<bool TAIL>
__global__ __launch_bounds__(256) void ln1_kernel(
    const ushort_t* __restrict__ hh_, const ushort_t* __restrict__ hl_,
    const float* __restrict__ bo,
    const int* __restrict__ slotmap, const float* __restrict__ adelta,
    ushort_t* __restrict__ oh, ushort_t* __restrict__ ol,
    const float* __restrict__ g, const float* __restrict__ bb){
  __shared__ float ss[4], qq[4];
  int r = blockIdx.x, tid = threadIdx.x;
  const int lane = tid & 63, wv = tid >> 6;
  int b, l;
  if (TAIL){ b = r / OUTLEN; l = TAIL0 + (r % OUTLEN); }
  else     { b = r >> 12;    l = r & (LL - 1); }
  const size_t gi = ((size_t)b * LL + l) * DD;
  const int j0 = 2 * tid;
  const uint_t hp = *(const uint_t*)(hh_ + gi + j0);
  const uint_t lp = *(const uint_t*)(hl_ + gi + j0);
  const float2 bo2 = *(const float2*)&bo[j0];
  float v0 = bf2f((ushort_t)(hp & 0xFFFF)) + bf2f((ushort_t)(lp & 0xFFFF)) + bo2.x;
  float v1 = bf2f((ushort_t)(hp >> 16))    + bf2f((ushort_t)(lp >> 16))    + bo2.y;
  int s = slotmap[b * LL + l];
  if (s >= 0){
    const float2 dr = *(const float2*)&adelta[((size_t)b * MAXSLOT + s) * DD + j0];
    v0 += dr.x; v1 += dr.y;
  }
  float sm = v0 + v1, qm = v0 * v0 + v1 * v1;
#pragma unroll
  for (int o2 = 32; o2 > 0; o2 >>= 1){ sm += __shfl_xor(sm, o2); qm += __shfl_xor(qm, o2); }
  if (lane == 0){ ss[wv] = sm; qq[wv] = qm; }
  __syncthreads();
  const float S = ss[0] + ss[1] + ss[2] + ss[3];
  const float Qv = qq[0] + qq[1] + qq[2] + qq[3];
  const float mu = S * (1.0f / DD);
  float var = Qv * (1.0f / DD) - mu * mu;
  const float rstd = rsqrtf(var + 1e-5f);
  const float2 g2 = *(const float2*)&g[j0];
  const float2 bb2 = *(const float2*)&bb[j0];
  float o0 = (v0 - mu) * rstd * g2.x + bb2.x;
  float o1 = (v1 - mu) * rstd * g2.y + bb2.y;
  const size_t oo = TAIL ? (size_t)r * DD : gi;
  ushort_t h0, l0, h1, l1;
  split2(o0, h0, l0); split2(o1, h1, l1);
  *(uint_t*)(oh + oo + j0) = (uint_t)h0 | ((uint_t)h1 << 16);
  *(uint_t*)(ol + oo + j0) = (uint_t)l0 | ((uint_t)l1 << 16);
}

// ---------- LN2: one-pass, two split-K partials ----------
template<bool TAIL>
__global__ __launch_bounds__(256) void ln2_kernel(
    const ushort_t* __restrict__ ih, const ushort_t* __restrict__ il,
    const float* __restrict__ pbuf, size_t pstr, const float* __restrict__ b2,
    ushort_t* __restrict__ oh, ushort_t* __restrict__ ol, float* __restrict__ ofp,
    const float* __restrict__ g, const float* __restrict__ bb, size_t rowoff){
  __shared__ float ss[4], qq[4];
  int r = blockIdx.x, tid = threadIdx.x;
  const int lane = tid & 63, wv = tid >> 6;
  const size_t gi = (rowoff + r) * DD;
  const size_t pi = (size_t)r * DD;
  const int j0 = 2 * tid;
  const uint_t hp = *(const uint_t*)(ih + gi + j0);
  const uint_t lp = *(const uint_t*)(il + gi + j0);
  const float2 p0 = *(const float2*)&pbuf[pi + j0];
  const float2 p1 = *(const float2*)&pbuf[pstr + pi + j0];
  const float2 b22 = *(const float2*)&b2[j0];
  float v0 = bf2f((ushort_t)(hp & 0xFFFF)) + bf2f((ushort_t)(lp & 0xFFFF)) + p0.x + p1.x + b22.x;
  float v1 = bf2f((ushort_t)(hp >> 16))    + bf2f((ushort_t)(lp >> 16))    + p0.y + p1.y + b22.y;
  float sm = v0 + v1, qm = v0 * v0 + v1 * v1;
#pragma unroll
  for (int o2 = 32; o2 > 0; o2 >>= 1){ sm += __shfl_xor(sm, o2); qm += __shfl_xor(qm, o2); }
  if (lane == 0){ ss[wv] = sm; qq[wv] = qm; }
  __syncthreads();
  const float S = ss[0] + ss[1] + ss[2] + ss[3];
  const float Qv = qq[0] + qq[1] + qq[2] + qq[3];
  const float mu = S * (1.0f / DD);
  float var = Qv * (1.0f / DD) - mu * mu;
  const float rstd = rsqrtf(var + 1e-5f);
  const float2 g2 = *(const float2*)&g[j0];
  const float2 bb2 = *(const float2*)&bb[j0];
  float o0 = (v0 - mu) * rstd * g2.x + bb2.x;
  float o1 = (v1 - mu) * rstd * g2.y + bb2.y;
  if (TAIL){
    ofp[pi + j0] = o0; ofp[pi + j0 + 1] = o1;
  } else {
    ushort_t h0, l0, h1, l1;
    split2(o0, h0, l0); split2(o1, h1, l1);
    *(uint_t*)(oh + gi + j0) = (uint_t)h0 | ((uint_t)h1 << 16);
    *(uint_t*)(ol + gi + j0) = (uint_t)l0 | ((uint_t)l1 << 16);
  }
}

// ---------- final ----------
__global__ __launch_bounds__(64) void pred_kernel(const float* __restrict__ ht,
    const float* __restrict__ wout, const float* __restrict__ bout, float* __restrict__ out){
  int r = blockIdx.x, lane = threadIdx.x;
  float acc = 0.f;
  for (int dd = lane; dd < DD; dd += 64) acc += ht[(size_t)r * DD + dd] * wout[dd];
  acc = wsum(acc);
  if (lane == 0) out[r] = acc + bout[0];
}

extern "C" void kernel_launch(void* const* d_in, const int* in_sizes, int n_in,
                              void* d_out, int out_size, void* d_ws, size_t ws_size,
                              hipStream_t stream){
  const float* x    = (const float*)d_in[0];
  const float* wemb = (const float*)d_in[1];
  const float* bemb = (const float*)d_in[2];
  const float* wq   = (const float*)d_in[3];
  const float* bq   = (const float*)d_in[4];
  const float* wk   = (const float*)d_in[5];
  const float* bk   = (const float*)d_in[6];
  const float* wv   = (const float*)d_in[7];
  const float* bvv  = (const float*)d_in[8];
  const float* wo   = (const float*)d_in[9];
  const float* bo   = (const float*)d_in[10];
  const float* w1   = (const float*)d_in[11];
  const float* b1   = (const float*)d_in[12];
  const float* w2   = (const float*)d_in[13];
  const float* b2   = (const float*)d_in[14];
  const float* g1   = (const float*)d_in[15];
  const float* be1  = (const float*)d_in[16];
  const float* g2   = (const float*)d_in[17];
  const float* be2  = (const float*)d_in[18];
  const float* wout = (const float*)d_in[19];
  const float* bout = (const float*)d_in[20];
  float* out = (float*)d_out;
  char* wsb  = (char*)d_ws;

  const size_t MiB = 1024 * 1024;
  const size_t NE  = (size_t)BB * LL * DD;   // 33.5M elems

  size_t o = 0;
  ushort_t* hh    = (ushort_t*)(wsb + o); o += NE * 2;          // 64 MiB
  ushort_t* hl    = (ushort_t*)(wsb + o); o += NE * 2;          // 64 MiB
  char*     arena = wsb + o;              o += 64 * MiB;        // shared arena
  // QKV phase:
  float*    qbuf  = (float*)arena;                              // 32 MiB
  ushort_t* kvbuf = (ushort_t*)(arena + 32 * MiB);              // 32 MiB
  // FFN phase (overlay):
  ushort_t* hid   = (ushort_t*)arena;                           // CH*DFF*2 = 32 MiB
  float*    pbuf  = (float*)(arena + 32 * MiB);                 // 2*CH*512*4 = 32 MiB
  // FFN tail overlay
  ushort_t* hidt  = (ushort_t*)arena;                           // 6 MiB
  float*    pbuft = (float*)(arena + 32 * MiB);                 // 6 MiB
  ushort_t* asht  = (ushort_t*)(arena + 48 * MiB);              // 1.5 MiB
  ushort_t* aslt  = (ushort_t*)(arena + 50 * MiB);              // 1.5 MiB
  // weights + small:
  ushort_t* wtqkvh = (ushort_t*)(wsb + o); o += (size_t)QKVN * DD * 2;
  ushort_t* wtqkvl = (ushort_t*)(wsb + o); o += (size_t)QKVN * DD * 2;
  ushort_t* w1th   = (ushort_t*)(wsb + o); o += (size_t)DFF * DD * 2;
  ushort_t* w2th   = (ushort_t*)(wsb + o); o += (size_t)DD * DFF * 2;
  ushort_t* w2tl   = (ushort_t*)(wsb + o); o += (size_t)DD * DFF * 2;
  ushort_t* w1tl   = (ushort_t*)(wsb + o); o += (size_t)DFF * DD * 2;  // scratch
  float*    bqkv   = (float*)(wsb + o);  o += QKVN * 4;
  float*    qsb    = (float*)(wsb + o);  o += (size_t)NB * HH * LL * 4;
  float*    part   = (float*)(wsb + o);  o += (size_t)NB * HH * UMAX * NSPLIT * PSTRIDE * 4;
  float*    adelta = (float*)(wsb + o);  o += (size_t)BB * MAXSLOT * DD * 4;
  float*    htail  = (float*)(wsb + o);  o += (size_t)NTAIL * DD * 4;
  int*      slotmap= (int*)(wsb + o);    o += (size_t)BB * LL * 4;
  int*      scount = (int*)(wsb + o);    o += BB * 4;
  int*      topidx = (int*)(wsb + o);    o += (size_t)BB * HH * UMAX * 4;
  int*      ufac   = (int*)(wsb + o);    o += 64;
  // total ~215 MiB (<= 234 proven-safe)

  wqkv_prep_kernel<<<dim3(QKVN/32, DD/32), 256, 0, stream>>>(wq, wk, wv, wtqkvh, wtqkvl);
  bqkv_prep_kernel<<<(QKVN + 255)/256, 256, 0, stream>>>(bq, bk, bvv, bqkv);
  wsplit_t_kernel<<<dim3(DFF/32, DD/32), 256, 0, stream>>>(w1, w1th, w1tl, DD, DFF);
  wsplit_t_kernel<<<dim3(DD/32, DFF/32), 256, 0, stream>>>(w2, w2th, w2tl, DFF, DD);

  embed_kernel<<<(BB * LL) / EROWS, 256, 0, stream>>>(x, wemb, bemb, hh, hl);

  for (int layer = 0; layer < 2; ++layer){
    const bool tail = (layer == 1);
    const int lmin = tail ? TAIL0 : 0;

    reset_kernel<<<1024, 256, 0, stream>>>(slotmap, scount, adelta);

    for (int qtr = 0; qtr < BB / NB; ++qtr){
      const size_t hoff = (size_t)qtr * QM * DD;
      gemm_qkv<<<dim3(QKVN/128, QM/128), 256, 0, stream>>>(
          hh + hoff, hl + hoff, wtqkvh, wtqkvl, bqkv, qbuf, kvbuf, qsb);
      select_kernel<<<dim3(9, NB), 256, 0, stream>>>(qsb, topidx, ufac, slotmap, scount, qtr);
      attn_p1_kernel<<<dim3(NSPLIT, HH, NB), 256, 0, stream>>>(
          qbuf, kvbuf, topidx, ufac, part, qtr, lmin);
      attn_p2_kernel<<<dim3(HH*UMAX, NB), 256, 0, stream>>>(
          part, wo, topidx, ufac, slotmap, adelta, qtr, lmin);
    }

    if (!tail){
      ln1_kernel<false><<<BB*LL, 256, 0, stream>>>(hh, hl, bo, slotmap, adelta, hh, hl, g1, be1);
      for (int c = 0; c < (BB*LL)/CH; ++c){
        const size_t roff = (size_t)c * CH;
        gemm_ffn1<<<dim3(DFF/128, CH/128), 256, 0, stream>>>(
            hh + roff * DD, hl + roff * DD, w1th, b1, hid);
        gemm_ffn2<<<dim3(8, CH/128), 256, 0, stream>>>(hid, w2th, w2tl, pbuf, (size_t)CH * DD);
        ln2_kernel<false><<<CH, 256, 0, stream>>>(
            hh, hl, pbuf, (size_t)CH * DD, b2, hh, hl, nullptr, g2, be2, roff);
      }
    } else {
      ln1_kernel<true><<<NTAIL, 256, 0, stream>>>(hh, hl, bo, slotmap, adelta, asht, aslt, g1, be1);
      gemm_ffn1<<<dim3(DFF/128, NTAIL/128), 256, 0, stream>>>(asht, aslt, w1th, b1, hidt);
      gemm_ffn2<<<dim3(8, NTAIL/128), 256, 0, stream>>>(hidt, w2th, w2tl, pbuft, (size_t)NTAIL * DD);
      ln2_kernel<true><<<NTAIL, 256, 0, stream>>>(
          asht, aslt, pbuft, (size_t)NTAIL * DD, b2, nullptr, nullptr, htail, g2, be2, 0);
      pred_kernel<<<NTAIL, 64, 0, stream>>>(htail, wout, bout, out);
    }
  }
  (void)in_sizes; (void)n_in; (void)out_size; (void)ws_size;
}

// Round 12
// 2521.313 us; speedup vs baseline: 1.0257x; 1.0257x over previous
//
#include <hip/hip_runtime.h>
#include <math.h>

#define BB 16
#define LL 4096
#define DIN 8
#define DD 512
#define HH 8
#define DKK 64
#define DFF 2048
#define OUTLEN 96
#define TAIL0 (LL - OUTLEN)   /* 4000 */
#define NTAIL (BB * OUTLEN)   /* 1536 */
#define UMAX 10
#define CH 8192               /* FFN row chunk */
#define QKVN 1536
#define NB 4                  /* batches per quarter */
#define QM (NB * LL)          /* 16384 rows per quarter */
#define NSPLIT 32
#define LCHUNK (LL / NSPLIT)  /* 128 */
#define PSTRIDE 68
#define MAXSLOT 128
#define EROWS 16

typedef unsigned short ushort_t;
typedef unsigned int uint_t;
typedef short bf16x8 __attribute__((ext_vector_type(8)));
typedef float f32x4 __attribute__((ext_vector_type(4)));

#define GLD16(gp, lp) __builtin_amdgcn_global_load_lds((const __attribute__((address_space(1))) void*)(gp), (__attribute__((address_space(3))) void*)(lp), 16, 0, 0)

// ---------- helpers ----------
__device__ inline float wsum(float v){
#pragma unroll
  for (int o = 32; o > 0; o >>= 1) v += __shfl_xor(v, o);
  return v;
}
__device__ inline ushort_t f2bf_rtn(float f){
  uint_t u = __float_as_uint(f);
  uint_t r = u + 0x7FFF + ((u >> 16) & 1);
  return (ushort_t)(r >> 16);
}
__device__ inline float bf2f(ushort_t u){
  return __uint_as_float(((uint_t)u) << 16);
}
__device__ inline void split2(float x, ushort_t& hi, ushort_t& lo){
  uint_t u = __float_as_uint(x);
  hi = (ushort_t)(u >> 16);
  lo = f2bf_rtn(x - __uint_as_float(u & 0xFFFF0000u));
}
// bijective XCD-chunked swizzle (m204)
__device__ inline void xcd_map(int& bx, int& by){
  const int gx = gridDim.x;
  const int nwg = gx * gridDim.y;
  const int wg = (int)blockIdx.y * gx + (int)blockIdx.x;
  const int q = nwg >> 3, r = nwg & 7;
  const int xcd = wg & 7, idx = wg >> 3;
  const int swz = (xcd < r ? xcd * (q + 1) : r * (q + 1) + (xcd - r) * q) + idx;
  bx = swz % gx; by = swz / gx;
}

// ---------- embed: 16 rows/block, packed stores ----------
__global__ __launch_bounds__(256) void embed_kernel(const float* __restrict__ x,
    const float* __restrict__ we, const float* __restrict__ be,
    ushort_t* __restrict__ hh, ushort_t* __restrict__ hl){
  const int row0 = blockIdx.x * EROWS;
  __shared__ float xs[EROWS][DIN];
  const int t = threadIdx.x;
  if (t < EROWS * DIN) xs[t >> 3][t & 7] = x[(size_t)row0 * DIN + t];
  __syncthreads();
  const int j0 = 2 * t;
  float w0[DIN], w1r[DIN];
#pragma unroll
  for (int i = 0; i < DIN; ++i){ w0[i] = we[i * DD + j0]; w1r[i] = we[i * DD + j0 + 1]; }
  const float b0 = be[j0], b1 = be[j0 + 1];
#pragma unroll
  for (int rr = 0; rr < EROWS; ++rr){
    float a0 = b0, a1 = b1;
#pragma unroll
    for (int i = 0; i < DIN; ++i){ a0 += xs[rr][i] * w0[i]; a1 += xs[rr][i] * w1r[i]; }
    ushort_t h0, l0, h1, l1;
    split2(a0, h0, l0); split2(a1, h1, l1);
    ((uint_t*)(hh + (size_t)(row0 + rr) * DD))[t] = (uint_t)h0 | ((uint_t)h1 << 16);
    ((uint_t*)(hl + (size_t)(row0 + rr) * DD))[t] = (uint_t)l0 | ((uint_t)l1 << 16);
  }
}

// ---------- weight prep: LDS 32x32 tile transpose ----------
__global__ __launch_bounds__(256) void wsplit_t_kernel(const float* __restrict__ W,
    ushort_t* __restrict__ Th, ushort_t* __restrict__ Tl, int K, int N){
  __shared__ float tile[32][33];
  const int n0 = blockIdx.x * 32;
  const int k0 = blockIdx.y * 32;
  const int tr = threadIdx.x >> 5;
  const int tc = threadIdx.x & 31;
#pragma unroll
  for (int rr = 0; rr < 4; ++rr)
    tile[tr + rr * 8][tc] = W[(size_t)(k0 + tr + rr * 8) * N + n0 + tc];
  __syncthreads();
#pragma unroll
  for (int rr = 0; rr < 4; ++rr){
    const int n = n0 + tr + rr * 8;
    ushort_t hi, lo;
    split2(tile[tc][tr + rr * 8], hi, lo);
    Th[(size_t)n * K + k0 + tc] = hi;
    Tl[(size_t)n * K + k0 + tc] = lo;
  }
}
__global__ __launch_bounds__(256) void wqkv_prep_kernel(const float* __restrict__ wq,
    const float* __restrict__ wk, const float* __restrict__ wv,
    ushort_t* __restrict__ Th, ushort_t* __restrict__ Tl){
  __shared__ float tile[32][33];
  const int n0 = blockIdx.x * 32;
  const int k0 = blockIdx.y * 32;
  const float* src = (n0 < 512) ? wq : (n0 < 1024) ? wk : wv;
  const int nb = n0 & 511;
  const int tr = threadIdx.x >> 5;
  const int tc = threadIdx.x & 31;
#pragma unroll
  for (int rr = 0; rr < 4; ++rr)
    tile[tr + rr * 8][tc] = src[(size_t)(k0 + tr + rr * 8) * DD + nb + tc];
  __syncthreads();
#pragma unroll
  for (int rr = 0; rr < 4; ++rr){
    const int n = n0 + tr + rr * 8;
    ushort_t hi, lo;
    split2(tile[tc][tr + rr * 8], hi, lo);
    Th[(size_t)n * DD + k0 + tc] = hi;
    Tl[(size_t)n * DD + k0 + tc] = lo;
  }
}
__global__ __launch_bounds__(256) void bqkv_prep_kernel(const float* __restrict__ bq,
    const float* __restrict__ bk, const float* __restrict__ bv, float* __restrict__ bo_){
  int n = blockIdx.x * 256 + threadIdx.x;
  if (n >= QKVN) return;
  bo_[n] = (n < 512) ? bq[n] : (n < 1024) ? bk[n - 512] : bv[n - 1024];
}

// ---------- QKV GEMM (round-10 verified: no qs fusion) ----------
__global__ __launch_bounds__(256) void gemm_qkv(
    const ushort_t* __restrict__ Ah, const ushort_t* __restrict__ Al,
    const ushort_t* __restrict__ Bh, const ushort_t* __restrict__ Bl,
    const float* __restrict__ bias, float* __restrict__ Q,
    ushort_t* __restrict__ KV){
  __shared__ __align__(16) ushort_t AsH[128 * 32];
  __shared__ __align__(16) ushort_t AsL[128 * 32];
  __shared__ __align__(16) ushort_t BsH[128 * 32];
  __shared__ __align__(16) ushort_t BsL[128 * 32];
  int bx, by; xcd_map(bx, by);
  const int tid  = threadIdx.x;
  const int lane = tid & 63;
  const int wv   = tid >> 6;
  const int m0   = by * 128;
  const int n0   = bx * 128;
  const bool isQ = (n0 < 512);
  const int wm   = (wv & 1) * 64;
  const int wn   = (wv >> 1) * 64;

  const int rowA = tid >> 2;
  const int qe   = (tid & 3) * 8;
  const int lds0 = tid * 8;
  const int lds1 = (tid + 256) * 8;

  f32x4 acc[4][4];
#pragma unroll
  for (int i = 0; i < 4; ++i)
#pragma unroll
    for (int j = 0; j < 4; ++j) acc[i][j] = (f32x4){0.f, 0.f, 0.f, 0.f};

  const int arow = lane & 15;
  const int koff = (lane >> 4) * 8;
  const int K = DD;

  for (int k0 = 0; k0 < K; k0 += 32){
    const size_t ga0 = (size_t)(m0 + rowA) * K + k0 + qe;
    const size_t ga1 = (size_t)(m0 + rowA + 64) * K + k0 + qe;
    const size_t gb0 = (size_t)(n0 + rowA) * K + k0 + qe;
    const size_t gb1 = (size_t)(n0 + rowA + 64) * K + k0 + qe;
    GLD16(Ah + ga0, &AsH[lds0]);  GLD16(Ah + ga1, &AsH[lds1]);
    GLD16(Al + ga0, &AsL[lds0]);  GLD16(Al + ga1, &AsL[lds1]);
    GLD16(Bh + gb0, &BsH[lds0]);  GLD16(Bh + gb1, &BsH[lds1]);
    if (isQ){ GLD16(Bl + gb0, &BsL[lds0]);  GLD16(Bl + gb1, &BsL[lds1]); }
    __syncthreads();

    bf16x8 ah[4], al[4], bh[4], bl[4];
#pragma unroll
    for (int i = 0; i < 4; ++i){
      ah[i] = *(const bf16x8*)&AsH[(wm + i * 16 + arow) * 32 + koff];
      al[i] = *(const bf16x8*)&AsL[(wm + i * 16 + arow) * 32 + koff];
      bh[i] = *(const bf16x8*)&BsH[(wn + i * 16 + arow) * 32 + koff];
      if (isQ) bl[i] = *(const bf16x8*)&BsL[(wn + i * 16 + arow) * 32 + koff];
    }
#pragma unroll
    for (int i = 0; i < 4; ++i)
#pragma unroll
      for (int j = 0; j < 4; ++j){
        acc[i][j] = __builtin_amdgcn_mfma_f32_16x16x32_bf16(ah[i], bh[j], acc[i][j], 0, 0, 0);
        acc[i][j] = __builtin_amdgcn_mfma_f32_16x16x32_bf16(al[i], bh[j], acc[i][j], 0, 0, 0);
        if (isQ)
          acc[i][j] = __builtin_amdgcn_mfma_f32_16x16x32_bf16(ah[i], bl[j], acc[i][j], 0, 0, 0);
      }
    __syncthreads();
  }

  const int crow = (lane >> 4) * 4;
  const int ccol = lane & 15;
#pragma unroll
  for (int i = 0; i < 4; ++i){
    const int gr0 = m0 + wm + i * 16 + crow;
#pragma unroll
    for (int j = 0; j < 4; ++j){
      const int gc = n0 + wn + j * 16 + ccol;
      const float bvv = bias[gc];
#pragma unroll
      for (int r = 0; r < 4; ++r){
        float v = acc[i][j][r] + bvv;
        const int gr = gr0 + r;
        if (isQ) Q[(size_t)gr * 512 + gc] = v;
        else     KV[(size_t)gr * 1024 + (gc - 512)] = f2bf_rtn(v);
      }
    }
  }
}

// ---------- FFN1: A split bf16, B=w1 hi only (x2), out = relu bf16 ----------
__global__ __launch_bounds__(256) void gemm_ffn1(
    const ushort_t* __restrict__ Ah, const ushort_t* __restrict__ Al,
    const ushort_t* __restrict__ Bh, const float* __restrict__ bias,
    ushort_t* __restrict__ Chid){
  __shared__ __align__(16) ushort_t AsH[128 * 32];
  __shared__ __align__(16) ushort_t AsL[128 * 32];
  __shared__ __align__(16) ushort_t BsH[128 * 32];
  int bx, by; xcd_map(bx, by);
  const int tid  = threadIdx.x;
  const int lane = tid & 63;
  const int wv   = tid >> 6;
  const int m0   = by * 128;
  const int n0   = bx * 128;
  const int wm   = (wv & 1) * 64;
  const int wn   = (wv >> 1) * 64;
  const int rowA = tid >> 2;
  const int qe   = (tid & 3) * 8;
  const int lds0 = tid * 8;
  const int lds1 = (tid + 256) * 8;

  f32x4 acc[4][4];
#pragma unroll
  for (int i = 0; i < 4; ++i)
#pragma unroll
    for (int j = 0; j < 4; ++j) acc[i][j] = (f32x4){0.f, 0.f, 0.f, 0.f};

  const int arow = lane & 15;
  const int koff = (lane >> 4) * 8;
  const int K = DD;

  for (int k0 = 0; k0 < K; k0 += 32){
    const size_t ga0 = (size_t)(m0 + rowA) * K + k0 + qe;
    const size_t ga1 = (size_t)(m0 + rowA + 64) * K + k0 + qe;
    const size_t gb0 = (size_t)(n0 + rowA) * K + k0 + qe;
    const size_t gb1 = (size_t)(n0 + rowA + 64) * K + k0 + qe;
    GLD16(Ah + ga0, &AsH[lds0]);  GLD16(Ah + ga1, &AsH[lds1]);
    GLD16(Al + ga0, &AsL[lds0]);  GLD16(Al + ga1, &AsL[lds1]);
    GLD16(Bh + gb0, &BsH[lds0]);  GLD16(Bh + gb1, &BsH[lds1]);
    __syncthreads();

    bf16x8 ah[4], al[4], bh[4];
#pragma unroll
    for (int i = 0; i < 4; ++i){
      ah[i] = *(const bf16x8*)&AsH[(wm + i * 16 + arow) * 32 + koff];
      al[i] = *(const bf16x8*)&AsL[(wm + i * 16 + arow) * 32 + koff];
      bh[i] = *(const bf16x8*)&BsH[(wn + i * 16 + arow) * 32 + koff];
    }
#pragma unroll
    for (int i = 0; i < 4; ++i)
#pragma unroll
      for (int j = 0; j < 4; ++j){
        acc[i][j] = __builtin_amdgcn_mfma_f32_16x16x32_bf16(ah[i], bh[j], acc[i][j], 0, 0, 0);
        acc[i][j] = __builtin_amdgcn_mfma_f32_16x16x32_bf16(al[i], bh[j], acc[i][j], 0, 0, 0);
      }
    __syncthreads();
  }

  const int crow = (lane >> 4) * 4;
  const int ccol = lane & 15;
#pragma unroll
  for (int i = 0; i < 4; ++i){
    const int gr0 = m0 + wm + i * 16 + crow;
#pragma unroll
    for (int j = 0; j < 4; ++j){
      const int gc = n0 + wn + j * 16 + ccol;
      const float bvv = bias[gc];
#pragma unroll
      for (int r = 0; r < 4; ++r){
        float v = fmaxf(acc[i][j][r] + bvv, 0.f);
        Chid[(size_t)(gr0 + r) * DFF + gc] = f2bf_rtn(v);
      }
    }
  }
}

// ---------- FFN2: A single bf16 (hid), B=w2 split (x2), split-K=2 partial fp32 out ----------
__global__ __launch_bounds__(256) void gemm_ffn2(
    const ushort_t* __restrict__ Ahid,
    const ushort_t* __restrict__ Bh, const ushort_t* __restrict__ Bl,
    float* __restrict__ pbuf, size_t pstr){
  __shared__ __align__(16) ushort_t AsH[128 * 32];
  __shared__ __align__(16) ushort_t BsH[128 * 32];
  __shared__ __align__(16) ushort_t BsL[128 * 32];
  int bx, by; xcd_map(bx, by);
  const int tid  = threadIdx.x;
  const int lane = tid & 63;
  const int wv   = tid >> 6;
  const int nblk = bx >> 1;
  const int kq   = bx & 1;
  const int m0   = by * 128;
  const int n0   = nblk * 128;
  const int wm   = (wv & 1) * 64;
  const int wn   = (wv >> 1) * 64;
  const int rowA = tid >> 2;
  const int qe   = (tid & 3) * 8;
  const int lds0 = tid * 8;
  const int lds1 = (tid + 256) * 8;

  f32x4 acc[4][4];
#pragma unroll
  for (int i = 0; i < 4; ++i)
#pragma unroll
    for (int j = 0; j < 4; ++j) acc[i][j] = (f32x4){0.f, 0.f, 0.f, 0.f};

  const int arow = lane & 15;
  const int koff = (lane >> 4) * 8;
  const int K = DFF;
  const int kper = K / 2;
  const int kbeg = kq * kper;

  for (int k0 = kbeg; k0 < kbeg + kper; k0 += 32){
    const size_t ga0 = (size_t)(m0 + rowA) * K + k0 + qe;
    const size_t ga1 = (size_t)(m0 + rowA + 64) * K + k0 + qe;
    const size_t gb0 = (size_t)(n0 + rowA) * K + k0 + qe;
    const size_t gb1 = (size_t)(n0 + rowA + 64) * K + k0 + qe;
    GLD16(Ahid + ga0, &AsH[lds0]);  GLD16(Ahid + ga1, &AsH[lds1]);
    GLD16(Bh + gb0, &BsH[lds0]);    GLD16(Bh + gb1, &BsH[lds1]);
    GLD16(Bl + gb0, &BsL[lds0]);    GLD16(Bl + gb1, &BsL[lds1]);
    __syncthreads();

    bf16x8 ah[4], bh[4], bl[4];
#pragma unroll
    for (int i = 0; i < 4; ++i){
      ah[i] = *(const bf16x8*)&AsH[(wm + i * 16 + arow) * 32 + koff];
      bh[i] = *(const bf16x8*)&BsH[(wn + i * 16 + arow) * 32 + koff];
      bl[i] = *(const bf16x8*)&BsL[(wn + i * 16 + arow) * 32 + koff];
    }
#pragma unroll
    for (int i = 0; i < 4; ++i)
#pragma unroll
      for (int j = 0; j < 4; ++j){
        acc[i][j] = __builtin_amdgcn_mfma_f32_16x16x32_bf16(ah[i], bh[j], acc[i][j], 0, 0, 0);
        acc[i][j] = __builtin_amdgcn_mfma_f32_16x16x32_bf16(ah[i], bl[j], acc[i][j], 0, 0, 0);
      }
    __syncthreads();
  }

  const int crow = (lane >> 4) * 4;
  const int ccol = lane & 15;
#pragma unroll
  for (int i = 0; i < 4; ++i){
    const int gr0 = m0 + wm + i * 16 + crow;
#pragma unroll
    for (int j = 0; j < 4; ++j){
      const int gc = n0 + wn + j * 16 + ccol;
#pragma unroll
      for (int r = 0; r < 4; ++r)
        pbuf[(size_t)kq * pstr + (size_t)(gr0 + r) * DD + gc] = acc[i][j][r];
    }
  }
}

// ---------- qs scoring, one quarter (standalone, high occupancy) ----------
__global__ __launch_bounds__(256) void qs_kernel(const float* __restrict__ qbuf, float* __restrict__ qsb){
  int tid = threadIdx.x;
  int lane = tid & 63;
  int wv = tid >> 6;
  int rid = blockIdx.x * 4 + wv;
  int bloc = rid >> 15;
  int hh = (rid >> 12) & 7;
  int l  = rid & (LL - 1);
  float qv = qbuf[((size_t)bloc * LL + l) * DD + hh * DKK + lane];
  float l2 = sqrtf(wsum(qv * qv));
  float mx = qv;
#pragma unroll
  for (int o = 32; o > 0; o >>= 1) mx = fmaxf(mx, __shfl_xor(mx, o));
  float e  = expf(qv - mx);
  float se = wsum(e);
  float p  = e / se;
  float ent = -wsum(p * logf(p + 1e-9f));
  float mu  = wsum(qv) * (1.0f / 64.0f);
  float dv  = qv - mu;
  float var = wsum(dv * dv) * (1.0f / 63.0f);
  float val = 0.5f * l2 + 0.3f * ent + 0.2f * var;
  if (lane == 0) qsb[(size_t)(bloc * HH + hh) * LL + l] = val;
}

// ---------- selection (incremental top-k) + fused slot allocation ----------
__global__ __launch_bounds__(256) void select_kernel(const float* __restrict__ qsb,
    int* __restrict__ topidx, int* __restrict__ ufac,
    int* __restrict__ slotmap, int* __restrict__ scount, int qtr){
  __shared__ float vals[LL];
  __shared__ float bv[256];
  __shared__ int   bi[256];
  __shared__ int   widx_s;
  __shared__ int   swin[UMAX];
  __shared__ double r1[256], r2[256];
  const int bloc = blockIdx.y;
  const int b = qtr * NB + bloc;
  int tid = threadIdx.x;
  if (blockIdx.x == 8){
    const float* row = qsb + (size_t)bloc * HH * LL;
    double s = 0.0, s2 = 0.0;
    for (int l = tid; l < LL; l += 256){ double v = row[l]; s += v; s2 += v * v; }
    r1[tid] = s; r2[tid] = s2; __syncthreads();
    for (int st = 128; st; st >>= 1){
      if (tid < st){ r1[tid] += r1[tid+st]; r2[tid] += r2[tid+st]; }
      __syncthreads();
    }
    if (tid == 0){
      double mean = r1[0] / (double)LL;
      double var  = (r2[0] - (double)LL * mean * mean) / (double)(LL - 1);
      if (var < 0.0) var = 0.0;
      double f = rint(sqrt(var) / (mean + 1e-6) * 10.0);
      if (f < 3.0) f = 3.0;
      if (f > 10.0) f = 10.0;
      ufac[b] = (int)f;
    }
    return;
  }
  int hh = blockIdx.x;
  const float* row = qsb + ((size_t)bloc * HH + hh) * LL;
  for (int l = tid; l < LL; l += 256) vals[l] = row[l];
  __syncthreads();
  float lmax = -INFINITY; int lidx = 0;
  for (int l = tid; l < LL; l += 256){
    float v = vals[l];
    if (v > lmax){ lmax = v; lidx = l; }
  }
  for (int it = 0; it < UMAX; ++it){
    bv[tid] = lmax; bi[tid] = lidx;
    __syncthreads();
    for (int st = 128; st; st >>= 1){
      if (tid < st){
        if (bv[tid+st] > bv[tid] || (bv[tid+st] == bv[tid] && bi[tid+st] < bi[tid])){
          bv[tid] = bv[tid+st]; bi[tid] = bi[tid+st];
        }
      }
      __syncthreads();
    }
    if (tid == 0){ topidx[(b * HH + hh) * UMAX + it] = bi[0]; widx_s = bi[0]; swin[it] = bi[0]; }
    __syncthreads();
    const int w = widx_s;
    if ((w & 255) == tid){
      vals[w] = -INFINITY;
      lmax = -INFINITY; lidx = 0;
      for (int l = tid; l < LL; l += 256){
        float v = vals[l];
        if (v > lmax){ lmax = v; lidx = l; }
      }
    }
    __syncthreads();
  }
  // fused slot allocation (allocating for rank>=u is harmless: adelta stays 0 there)
  if (tid < UMAX){
    int qpos = swin[tid];
    int* cell = &slotmap[b * LL + qpos];
    int old = atomicCAS(cell, -1, -2);
    if (old == -1){
      int s = atomicAdd(&scount[b], 1);
      atomicExch(cell, s);
    }
  }
}

// ---------- reset: slotmap=-1, scount=0, adelta=0 ----------
__global__ void reset_kernel(int* __restrict__ slotmap, int* __restrict__ scount,
    float* __restrict__ adelta){
  size_t i = (size_t)blockIdx.x * 256 + threadIdx.x;
  size_t stride = (size_t)gridDim.x * 256;
  for (size_t k = i; k < (size_t)BB * LL; k += stride) slotmap[k] = -1;
  for (size_t k = i; k < (size_t)BB * MAXSLOT * DD; k += stride) adelta[k] = 0.f;
  if (i < BB) scount[i] = 0;
}

// ---------- attention pass 1: K/V in regs once, loop over ranks ----------
__global__ __launch_bounds__(256) void attn_p1_kernel(const float* __restrict__ qbuf,
    const ushort_t* __restrict__ kvbuf,
    const int* __restrict__ topidx, const int* __restrict__ ufac,
    float* __restrict__ part, int qtr, int lmin){
  const int bloc = blockIdx.z;
  const int b = qtr * NB + bloc;
  const int hh = blockIdx.y;
  const int u = ufac[b];
  const int tid = threadIdx.x, lane = tid & 63, wv = tid >> 6;
  const int base = blockIdx.x * LCHUNK + wv * 32;

  const ushort_t* Kp = kvbuf + (size_t)bloc * LL * 1024 + hh * DKK + lane;
  const ushort_t* Vp = Kp + 512;
  float kreg[32], vreg[32];
#pragma unroll
  for (int i = 0; i < 32; ++i){
    kreg[i] = bf2f(Kp[(size_t)(base + i) * 1024]);
    vreg[i] = bf2f(Vp[(size_t)(base + i) * 1024]);
  }

  __shared__ float wm4[4], ws4[4];
  __shared__ float pvs[4][DKK];

  for (int rank = 0; rank < u; ++rank){
    const int qpos = topidx[(b * HH + hh) * UMAX + rank];
    if (qpos < lmin) continue;
    const float qv = qbuf[((size_t)bloc * LL + qpos) * DD + hh * DKK + lane];

    float sc[32];
    float mloc = -INFINITY;
#pragma unroll
    for (int i = 0; i < 32; ++i){
      float s = wsum(qv * kreg[i]) * 0.125f;
      sc[i] = s;
      mloc = fmaxf(mloc, s);
    }
    if (lane == 0) wm4[wv] = mloc;
    __syncthreads();
    const float M4 = fmaxf(fmaxf(wm4[0], wm4[1]), fmaxf(wm4[2], wm4[3]));

    float ssum = 0.f;
#pragma unroll
    for (int i = 0; i < 32; ++i){ float e = expf(sc[i] - M4); sc[i] = e; ssum += e; }

    float pv = 0.f;
#pragma unroll
    for (int i = 0; i < 32; ++i) pv += sc[i] * vreg[i];

    pvs[wv][lane] = pv;
    if (lane == 0) ws4[wv] = ssum;
    __syncthreads();
    if (wv == 0){
      const int rowid = hh * UMAX + rank;
      float* rec = part + (size_t)((bloc * HH * UMAX + rowid) * NSPLIT + blockIdx.x) * PSTRIDE;
      rec[lane] = pvs[0][lane] + pvs[1][lane] + pvs[2][lane] + pvs[3][lane];
      if (lane == 0){ rec[64] = M4; rec[65] = ws4[0] + ws4[1] + ws4[2] + ws4[3]; }
    }
    __syncthreads();
  }
}

// ---------- attention pass 2: combine + wo projection -> adelta ----------
__global__ __launch_bounds__(256) void attn_p2_kernel(const float* __restrict__ part,
    const float* __restrict__ wo, const int* __restrict__ topidx, const int* __restrict__ ufac,
    const int* __restrict__ slotmap, float* __restrict__ adelta, int qtr, int lmin){
  const int bloc = blockIdx.y;
  const int b = qtr * NB + bloc;
  const int rowid = blockIdx.x;
  const int hh = rowid / UMAX, rank = rowid % UMAX;
  if (rank >= ufac[b]) return;
  const int qpos = topidx[(b * HH + hh) * UMAX + rank];
  if (qpos < lmin) return;
  const int slot = slotmap[b * LL + qpos];

  const int tid = threadIdx.x;
  const float* pbase = part + (size_t)(bloc * HH * UMAX + rowid) * NSPLIT * PSTRIDE;
  __shared__ float pm[NSPLIT], ps[NSPLIT];
  __shared__ float orow[DKK];
  if (tid < NSPLIT){
    pm[tid] = pbase[(size_t)tid * PSTRIDE + 64];
    ps[tid] = pbase[(size_t)tid * PSTRIDE + 65];
  }
  __syncthreads();
  float M = -INFINITY;
#pragma unroll
  for (int i = 0; i < NSPLIT; ++i) M = fmaxf(M, pm[i]);
  float S = 0.f;
#pragma unroll
  for (int i = 0; i < NSPLIT; ++i) S += ps[i] * expf(pm[i] - M);
  if (tid < DKK){
    float acc = 0.f;
#pragma unroll
    for (int i = 0; i < NSPLIT; ++i)
      acc += pbase[(size_t)i * PSTRIDE + tid] * expf(pm[i] - M);
    orow[tid] = acc / S;
  }
  __syncthreads();
  float* drow = adelta + ((size_t)b * MAXSLOT + slot) * DD;
  for (int j = tid; j < DD; j += 256){
    float a = 0.f;
#pragma unroll
    for (int dd = 0; dd < DKK; ++dd) a += orow[dd] * wo[(size_t)(hh * DKK + dd) * DD + j];
    atomicAdd(&drow[j], a);
  }
}

// ---------- LN1: one-pass sum/sumsq, wave reduce ----------
template<bool TAIL>
__global__ __launch_bounds__(256) void ln1_kernel(
    const ushort_t* __restrict__ hh_, const ushort_t* __restrict__ hl_,
    const float* __restrict__ bo,
    const int* __restrict__ slotmap, const float* __restrict__ adelta,
    ushort_t* __restrict__ oh, ushort_t* __restrict__ ol,
    const float* __restrict__ g, const float* __restrict__ bb){
  __shared__ float ss[4], qq[4];
  int r = blockIdx.x, tid = threadIdx.x;
  const int lane = tid & 63, wv = tid >> 6;
  int b, l;
  if (TAIL){ b = r / OUTLEN; l = TAIL0 + (r % OUTLEN); }
  else     { b = r >> 12;    l = r & (LL - 1); }
  const size_t gi = ((size_t)b * LL + l) * DD;
  const int j0 = 2 * tid;
  const uint_t hp = *(const uint_t*)(hh_ + gi + j0);
  const uint_t lp = *(const uint_t*)(hl_ + gi + j0);
  const float2 bo2 = *(const float2*)&bo[j0];
  float v0 = bf2f((ushort_t)(hp & 0xFFFF)) + bf2f((ushort_t)(lp & 0xFFFF)) + bo2.x;
  float v1 = bf2f((ushort_t)(hp >> 16))    + bf2f((ushort_t)(lp >> 16))    + bo2.y;
  int s = slotmap[b * LL + l];
  if (s >= 0){
    const float2 dr = *(const float2*)&adelta[((size_t)b * MAXSLOT + s) * DD + j0];
    v0 += dr.x; v1 += dr.y;
  }
  float sm = v0 + v1, qm = v0 * v0 + v1 * v1;
#pragma unroll
  for (int o2 = 32; o2 > 0; o2 >>= 1){ sm += __shfl_xor(sm, o2); qm += __shfl_xor(qm, o2); }
  if (lane == 0){ ss[wv] = sm; qq[wv] = qm; }
  __syncthreads();
  const float S = ss[0] + ss[1] + ss[2] + ss[3];
  const float Qv = qq[0] + qq[1] + qq[2] + qq[3];
  const float mu = S * (1.0f / DD);
  float var = Qv * (1.0f / DD) - mu * mu;
  const float rstd = rsqrtf(var + 1e-5f);
  const float2 g2 = *(const float2*)&g[j0];
  const float2 bb2 = *(const float2*)&bb[j0];
  float o0 = (v0 - mu) * rstd * g2.x + bb2.x;
  float o1 = (v1 - mu) * rstd * g2.y + bb2.y;
  const size_t oo = TAIL ? (size_t)r * DD : gi;
  ushort_t h0, l0, h1, l1;
  split2(o0, h0, l0); split2(o1, h1, l1);
  *(uint_t*)(oh + oo + j0) = (uint_t)h0 | ((uint_t)h1 << 16);
  *(uint_t*)(ol + oo + j0) = (uint_t)l0 | ((uint_t)l1 << 16);
}

// ---------- LN2: one-pass, two split-K partials ----------
template<bool TAIL>
__global__ __launch_bounds__(256) void ln2_kernel(
    const ushort_t* __restrict__ ih, const ushort_t* __restrict__ il,
    const float* __restrict__ pbuf, size_t pstr, const float* __restrict__ b2,
    ushort_t* __restrict__ oh, ushort_t* __restrict__ ol, float* __restrict__ ofp,
    const float* __restrict__ g, const float* __restrict__ bb, size_t rowoff){
  __shared__ float ss[4], qq[4];
  int r = blockIdx.x, tid = threadIdx.x;
  const int lane = tid & 63, wv = tid >> 6;
  const size_t gi = (rowoff + r) * DD;
  const size_t pi = (size_t)r * DD;
  const int j0 = 2 * tid;
  const uint_t hp = *(const uint_t*)(ih + gi + j0);
  const uint_t lp = *(const uint_t*)(il + gi + j0);
  const float2 p0 = *(const float2*)&pbuf[pi + j0];
  const float2 p1 = *(const float2*)&pbuf[pstr + pi + j0];
  const float2 b22 = *(const float2*)&b2[j0];
  float v0 = bf2f((ushort_t)(hp & 0xFFFF)) + bf2f((ushort_t)(lp & 0xFFFF)) + p0.x + p1.x + b22.x;
  float v1 = bf2f((ushort_t)(hp >> 16))    + bf2f((ushort_t)(lp >> 16))    + p0.y + p1.y + b22.y;
  float sm = v0 + v1, qm = v0 * v0 + v1 * v1;
#pragma unroll
  for (int o2 = 32; o2 > 0; o2 >>= 1){ sm += __shfl_xor(sm, o2); qm += __shfl_xor(qm, o2); }
  if (lane == 0){ ss[wv] = sm; qq[wv] = qm; }
  __syncthreads();
  const float S = ss[0] + ss[1] + ss[2] + ss[3];
  const float Qv = qq[0] + qq[1] + qq[2] + qq[3];
  const float mu = S * (1.0f / DD);
  float var = Qv * (1.0f / DD) - mu * mu;
  const float rstd = rsqrtf(var + 1e-5f);
  const float2 g2 = *(const float2*)&g[j0];
  const float2 bb2 = *(const float2*)&bb[j0];
  float o0 = (v0 - mu) * rstd * g2.x + bb2.x;
  float o1 = (v1 - mu) * rstd * g2.y + bb2.y;
  if (TAIL){
    ofp[pi + j0] = o0; ofp[pi + j0 + 1] = o1;
  } else {
    ushort_t h0, l0, h1, l1;
    split2(o0, h0, l0); split2(o1, h1, l1);
    *(uint_t*)(oh + gi + j0) = (uint_t)h0 | ((uint_t)h1 << 16);
    *(uint_t*)(ol + gi + j0) = (uint_t)l0 | ((uint_t)l1 << 16);
  }
}

// ---------- final ----------
__global__ __launch_bounds__(64) void pred_kernel(const float* __restrict__ ht,
    const float* __restrict__ wout, const float* __restrict__ bout, float* __restrict__ out){
  int r = blockIdx.x, lane = threadIdx.x;
  float acc = 0.f;
  for (int dd = lane; dd < DD; dd += 64) acc += ht[(size_t)r * DD + dd] * wout[dd];
  acc = wsum(acc);
  if (lane == 0) out[r] = acc + bout[0];
}

extern "C" void kernel_launch(void* const* d_in, const int* in_sizes, int n_in,
                              void* d_out, int out_size, void* d_ws, size_t ws_size,
                              hipStream_t stream){
  const float* x    = (const float*)d_in[0];
  const float* wemb = (const float*)d_in[1];
  const float* bemb = (const float*)d_in[2];
  const float* wq   = (const float*)d_in[3];
  const float* bq   = (const float*)d_in[4];
  const float* wk   = (const float*)d_in[5];
  const float* bk   = (const float*)d_in[6];
  const float* wv   = (const float*)d_in[7];
  const float* bvv  = (const float*)d_in[8];
  const float* wo   = (const float*)d_in[9];
  const float* bo   = (const float*)d_in[10];
  const float* w1   = (const float*)d_in[11];
  const float* b1   = (const float*)d_in[12];
  const float* w2   = (const float*)d_in[13];
  const float* b2   = (const float*)d_in[14];
  const float* g1   = (const float*)d_in[15];
  const float* be1  = (const float*)d_in[16];
  const float* g2   = (const float*)d_in[17];
  const float* be2  = (const float*)d_in[18];
  const float* wout = (const float*)d_in[19];
  const float* bout = (const float*)d_in[20];
  float* out = (float*)d_out;
  char* wsb  = (char*)d_ws;

  const size_t MiB = 1024 * 1024;
  const size_t NE  = (size_t)BB * LL * DD;   // 33.5M elems

  size_t o = 0;
  ushort_t* hh    = (ushort_t*)(wsb + o); o += NE * 2;          // 64 MiB
  ushort_t* hl    = (ushort_t*)(wsb + o); o += NE * 2;          // 64 MiB
  char*     arena = wsb + o;              o += 64 * MiB;        // shared arena
  // QKV phase:
  float*    qbuf  = (float*)arena;                              // 32 MiB
  ushort_t* kvbuf = (ushort_t*)(arena + 32 * MiB);              // 32 MiB
  // FFN phase (overlay):
  ushort_t* hid   = (ushort_t*)arena;                           // CH*DFF*2 = 32 MiB
  float*    pbuf  = (float*)(arena + 32 * MiB);                 // 2*CH*512*4 = 32 MiB
  // FFN tail overlay
  ushort_t* hidt  = (ushort_t*)arena;                           // 6 MiB
  float*    pbuft = (float*)(arena + 32 * MiB);                 // 6 MiB
  ushort_t* asht  = (ushort_t*)(arena + 48 * MiB);              // 1.5 MiB
  ushort_t* aslt  = (ushort_t*)(arena + 50 * MiB);              // 1.5 MiB
  // weights + small:
  ushort_t* wtqkvh = (ushort_t*)(wsb + o); o += (size_t)QKVN * DD * 2;
  ushort_t* wtqkvl = (ushort_t*)(wsb + o); o += (size_t)QKVN * DD * 2;
  ushort_t* w1th   = (ushort_t*)(wsb + o); o += (size_t)DFF * DD * 2;
  ushort_t* w2th   = (ushort_t*)(wsb + o); o += (size_t)DD * DFF * 2;
  ushort_t* w2tl   = (ushort_t*)(wsb + o); o += (size_t)DD * DFF * 2;
  ushort_t* w1tl   = (ushort_t*)(wsb + o); o += (size_t)DFF * DD * 2;  // scratch
  float*    bqkv   = (float*)(wsb + o);  o += QKVN * 4;
  float*    qsb    = (float*)(wsb + o);  o += (size_t)NB * HH * LL * 4;
  float*    part   = (float*)(wsb + o);  o += (size_t)NB * HH * UMAX * NSPLIT * PSTRIDE * 4;
  float*    adelta = (float*)(wsb + o);  o += (size_t)BB * MAXSLOT * DD * 4;
  float*    htail  = (float*)(wsb + o);  o += (size_t)NTAIL * DD * 4;
  int*      slotmap= (int*)(wsb + o);    o += (size_t)BB * LL * 4;
  int*      scount = (int*)(wsb + o);    o += BB * 4;
  int*      topidx = (int*)(wsb + o);    o += (size_t)BB * HH * UMAX * 4;
  int*      ufac   = (int*)(wsb + o);    o += 64;
  // total ~215 MiB (<= 234 proven-safe)

  wqkv_prep_kernel<<<dim3(QKVN/32, DD/32), 256, 0, stream>>>(wq, wk, wv, wtqkvh, wtqkvl);
  bqkv_prep_kernel<<<(QKVN + 255)/256, 256, 0, stream>>>(bq, bk, bvv, bqkv);
  wsplit_t_kernel<<<dim3(DFF/32, DD/32), 256, 0, stream>>>(w1, w1th, w1tl, DD, DFF);
  wsplit_t_kernel<<<dim3(DD/32, DFF/32), 256, 0, stream>>>(w2, w2th, w2tl, DFF, DD);

  embed_kernel<<<(BB * LL) / EROWS, 256, 0, stream>>>(x, wemb, bemb, hh, hl);

  for (int layer = 0; layer < 2; ++layer){
    const bool tail = (layer == 1);
    const int lmin = tail ? TAIL0 : 0;

    reset_kernel<<<1024, 256, 0, stream>>>(slotmap, scount, adelta);

    for (int qtr = 0; qtr < BB / NB; ++qtr){
      const size_t hoff = (size_t)qtr * QM * DD;
      gemm_qkv<<<dim3(QKVN/128, QM/128), 256, 0, stream>>>(
          hh + hoff, hl + hoff, wtqkvh, wtqkvl, bqkv, qbuf, kvbuf);
      qs_kernel<<<(NB*HH*LL)/4, 256, 0, stream>>>(qbuf, qsb);
      select_kernel<<<dim3(9, NB), 256, 0, stream>>>(qsb, topidx, ufac, slotmap, scount, qtr);
      attn_p1_kernel<<<dim3(NSPLIT, HH, NB), 256, 0, stream>>>(
          qbuf, kvbuf, topidx, ufac, part, qtr, lmin);
      attn_p2_kernel<<<dim3(HH*UMAX, NB), 256, 0, stream>>>(
          part, wo, topidx, ufac, slotmap, adelta, qtr, lmin);
    }

    if (!tail){
      ln1_kernel<false><<<BB*LL, 256, 0, stream>>>(hh, hl, bo, slotmap, adelta, hh, hl, g1, be1);
      for (int c = 0; c < (BB*LL)/CH; ++c){
        const size_t roff = (size_t)c * CH;
        gemm_ffn1<<<dim3(DFF/128, CH/128), 256, 0, stream>>>(
            hh + roff * DD, hl + roff * DD, w1th, b1, hid);
        gemm_ffn2<<<dim3(8, CH/128), 256, 0, stream>>>(hid, w2th, w2tl, pbuf, (size_t)CH * DD);
        ln2_kernel<false><<<CH, 256, 0, stream>>>(
            hh, hl, pbuf, (size_t)CH * DD, b2, hh, hl, nullptr, g2, be2, roff);
      }
    } else {
      ln1_kernel<true><<<NTAIL, 256, 0, stream>>>(hh, hl, bo, slotmap, adelta, asht, aslt, g1, be1);
      gemm_ffn1<<<dim3(DFF/128, NTAIL/128), 256, 0, stream>>>(asht, aslt, w1th, b1, hidt);
      gemm_ffn2<<<dim3(8, NTAIL/128), 256, 0, stream>>>(hidt, w2th, w2tl, pbuft, (size_t)NTAIL * DD);
      ln2_kernel<true><<<NTAIL, 256, 0, stream>>>(
          asht, aslt, pbuft, (size_t)NTAIL * DD, b2, nullptr, nullptr, htail, g2, be2, 0);
      pred_kernel<<<NTAIL, 64, 0, stream>>>(htail, wout, bout, out);
    }
  }
  (void)in_sizes; (void)n_in; (void)out_size; (void)ws_size;
}

// Round 13
// 2520.199 us; speedup vs baseline: 1.0262x; 1.0004x over previous
//
#include <hip/hip_runtime.h>
#include <math.h>

#define BB 16
#define LL 4096
#define DIN 8
#define DD 512
#define HH 8
#define DKK 64
#define DFF 2048
#define OUTLEN 96
#define TAIL0 (LL - OUTLEN)   /* 4000 */
#define NTAIL (BB * OUTLEN)   /* 1536 */
#define UMAX 10
#define CH 8192               /* FFN row chunk */
#define QKVN 1536
#define NB 4                  /* batches per quarter */
#define QM (NB * LL)          /* 16384 rows per quarter */
#define NSPLIT 32
#define LCHUNK (LL / NSPLIT)  /* 128 */
#define PSTRIDE 68
#define MAXSLOT 128
#define EROWS 16

typedef unsigned short ushort_t;
typedef unsigned int uint_t;
typedef short bf16x8 __attribute__((ext_vector_type(8)));
typedef float f32x4 __attribute__((ext_vector_type(4)));

#define GLD16(gp, lp) __builtin_amdgcn_global_load_lds((const __attribute__((address_space(1))) void*)(gp), (__attribute__((address_space(3))) void*)(lp), 16, 0, 0)

// ---------- helpers ----------
__device__ inline float wsum(float v){
#pragma unroll
  for (int o = 32; o > 0; o >>= 1) v += __shfl_xor(v, o);
  return v;
}
__device__ inline ushort_t f2bf_rtn(float f){
  uint_t u = __float_as_uint(f);
  uint_t r = u + 0x7FFF + ((u >> 16) & 1);
  return (ushort_t)(r >> 16);
}
__device__ inline float bf2f(ushort_t u){
  return __uint_as_float(((uint_t)u) << 16);
}
__device__ inline void split2(float x, ushort_t& hi, ushort_t& lo){
  uint_t u = __float_as_uint(x);
  hi = (ushort_t)(u >> 16);
  lo = f2bf_rtn(x - __uint_as_float(u & 0xFFFF0000u));
}
// bijective XCD-chunked swizzle (m204)
__device__ inline void xcd_map(int& bx, int& by){
  const int gx = gridDim.x;
  const int nwg = gx * gridDim.y;
  const int wg = (int)blockIdx.y * gx + (int)blockIdx.x;
  const int q = nwg >> 3, r = nwg & 7;
  const int xcd = wg & 7, idx = wg >> 3;
  const int swz = (xcd < r ? xcd * (q + 1) : r * (q + 1) + (xcd - r) * q) + idx;
  bx = swz % gx; by = swz / gx;
}

// ---------- embed: 16 rows/block, packed stores ----------
__global__ __launch_bounds__(256) void embed_kernel(const float* __restrict__ x,
    const float* __restrict__ we, const float* __restrict__ be,
    ushort_t* __restrict__ hh, ushort_t* __restrict__ hl){
  const int row0 = blockIdx.x * EROWS;
  __shared__ float xs[EROWS][DIN];
  const int t = threadIdx.x;
  if (t < EROWS * DIN) xs[t >> 3][t & 7] = x[(size_t)row0 * DIN + t];
  __syncthreads();
  const int j0 = 2 * t;
  float w0[DIN], w1r[DIN];
#pragma unroll
  for (int i = 0; i < DIN; ++i){ w0[i] = we[i * DD + j0]; w1r[i] = we[i * DD + j0 + 1]; }
  const float b0 = be[j0], b1 = be[j0 + 1];
#pragma unroll
  for (int rr = 0; rr < EROWS; ++rr){
    float a0 = b0, a1 = b1;
#pragma unroll
    for (int i = 0; i < DIN; ++i){ a0 += xs[rr][i] * w0[i]; a1 += xs[rr][i] * w1r[i]; }
    ushort_t h0, l0, h1, l1;
    split2(a0, h0, l0); split2(a1, h1, l1);
    ((uint_t*)(hh + (size_t)(row0 + rr) * DD))[t] = (uint_t)h0 | ((uint_t)h1 << 16);
    ((uint_t*)(hl + (size_t)(row0 + rr) * DD))[t] = (uint_t)l0 | ((uint_t)l1 << 16);
  }
}

// ---------- weight prep: LDS 32x32 tile transpose ----------
__global__ __launch_bounds__(256) void wsplit_t_kernel(const float* __restrict__ W,
    ushort_t* __restrict__ Th, ushort_t* __restrict__ Tl, int K, int N){
  __shared__ float tile[32][33];
  const int n0 = blockIdx.x * 32;
  const int k0 = blockIdx.y * 32;
  const int tr = threadIdx.x >> 5;
  const int tc = threadIdx.x & 31;
#pragma unroll
  for (int rr = 0; rr < 4; ++rr)
    tile[tr + rr * 8][tc] = W[(size_t)(k0 + tr + rr * 8) * N + n0 + tc];
  __syncthreads();
#pragma unroll
  for (int rr = 0; rr < 4; ++rr){
    const int n = n0 + tr + rr * 8;
    ushort_t hi, lo;
    split2(tile[tc][tr + rr * 8], hi, lo);
    Th[(size_t)n * K + k0 + tc] = hi;
    Tl[(size_t)n * K + k0 + tc] = lo;
  }
}
__global__ __launch_bounds__(256) void wqkv_prep_kernel(const float* __restrict__ wq,
    const float* __restrict__ wk, const float* __restrict__ wv,
    ushort_t* __restrict__ Th, ushort_t* __restrict__ Tl){
  __shared__ float tile[32][33];
  const int n0 = blockIdx.x * 32;
  const int k0 = blockIdx.y * 32;
  const float* src = (n0 < 512) ? wq : (n0 < 1024) ? wk : wv;
  const int nb = n0 & 511;
  const int tr = threadIdx.x >> 5;
  const int tc = threadIdx.x & 31;
#pragma unroll
  for (int rr = 0; rr < 4; ++rr)
    tile[tr + rr * 8][tc] = src[(size_t)(k0 + tr + rr * 8) * DD + nb + tc];
  __syncthreads();
#pragma unroll
  for (int rr = 0; rr < 4; ++rr){
    const int n = n0 + tr + rr * 8;
    ushort_t hi, lo;
    split2(tile[tc][tr + rr * 8], hi, lo);
    Th[(size_t)n * DD + k0 + tc] = hi;
    Tl[(size_t)n * DD + k0 + tc] = lo;
  }
}
__global__ __launch_bounds__(256) void bqkv_prep_kernel(const float* __restrict__ bq,
    const float* __restrict__ bk, const float* __restrict__ bv, float* __restrict__ bo_){
  int n = blockIdx.x * 256 + threadIdx.x;
  if (n >= QKVN) return;
  bo_[n] = (n < 512) ? bq[n] : (n < 1024) ? bk[n - 512] : bv[n - 1024];
}

// ---------- QKV GEMM (verified best: no qs fusion) ----------
__global__ __launch_bounds__(256) void gemm_qkv(
    const ushort_t* __restrict__ Ah, const ushort_t* __restrict__ Al,
    const ushort_t* __restrict__ Bh, const ushort_t* __restrict__ Bl,
    const float* __restrict__ bias, float* __restrict__ Q,
    ushort_t* __restrict__ KV){
  __shared__ __align__(16) ushort_t AsH[128 * 32];
  __shared__ __align__(16) ushort_t AsL[128 * 32];
  __shared__ __align__(16) ushort_t BsH[128 * 32];
  __shared__ __align__(16) ushort_t BsL[128 * 32];
  int bx, by; xcd_map(bx, by);
  const int tid  = threadIdx.x;
  const int lane = tid & 63;
  const int wv   = tid >> 6;
  const int m0   = by * 128;
  const int n0   = bx * 128;
  const bool isQ = (n0 < 512);
  const int wm   = (wv & 1) * 64;
  const int wn   = (wv >> 1) * 64;

  const int rowA = tid >> 2;
  const int qe   = (tid & 3) * 8;
  const int lds0 = tid * 8;
  const int lds1 = (tid + 256) * 8;

  f32x4 acc[4][4];
#pragma unroll
  for (int i = 0; i < 4; ++i)
#pragma unroll
    for (int j = 0; j < 4; ++j) acc[i][j] = (f32x4){0.f, 0.f, 0.f, 0.f};

  const int arow = lane & 15;
  const int koff = (lane >> 4) * 8;
  const int K = DD;

  for (int k0 = 0; k0 < K; k0 += 32){
    const size_t ga0 = (size_t)(m0 + rowA) * K + k0 + qe;
    const size_t ga1 = (size_t)(m0 + rowA + 64) * K + k0 + qe;
    const size_t gb0 = (size_t)(n0 + rowA) * K + k0 + qe;
    const size_t gb1 = (size_t)(n0 + rowA + 64) * K + k0 + qe;
    GLD16(Ah + ga0, &AsH[lds0]);  GLD16(Ah + ga1, &AsH[lds1]);
    GLD16(Al + ga0, &AsL[lds0]);  GLD16(Al + ga1, &AsL[lds1]);
    GLD16(Bh + gb0, &BsH[lds0]);  GLD16(Bh + gb1, &BsH[lds1]);
    if (isQ){ GLD16(Bl + gb0, &BsL[lds0]);  GLD16(Bl + gb1, &BsL[lds1]); }
    __syncthreads();

    bf16x8 ah[4], al[4], bh[4], bl[4];
#pragma unroll
    for (int i = 0; i < 4; ++i){
      ah[i] = *(const bf16x8*)&AsH[(wm + i * 16 + arow) * 32 + koff];
      al[i] = *(const bf16x8*)&AsL[(wm + i * 16 + arow) * 32 + koff];
      bh[i] = *(const bf16x8*)&BsH[(wn + i * 16 + arow) * 32 + koff];
      if (isQ) bl[i] = *(const bf16x8*)&BsL[(wn + i * 16 + arow) * 32 + koff];
    }
#pragma unroll
    for (int i = 0; i < 4; ++i)
#pragma unroll
      for (int j = 0; j < 4; ++j){
        acc[i][j] = __builtin_amdgcn_mfma_f32_16x16x32_bf16(ah[i], bh[j], acc[i][j], 0, 0, 0);
        acc[i][j] = __builtin_amdgcn_mfma_f32_16x16x32_bf16(al[i], bh[j], acc[i][j], 0, 0, 0);
        if (isQ)
          acc[i][j] = __builtin_amdgcn_mfma_f32_16x16x32_bf16(ah[i], bl[j], acc[i][j], 0, 0, 0);
      }
    __syncthreads();
  }

  const int crow = (lane >> 4) * 4;
  const int ccol = lane & 15;
#pragma unroll
  for (int i = 0; i < 4; ++i){
    const int gr0 = m0 + wm + i * 16 + crow;
#pragma unroll
    for (int j = 0; j < 4; ++j){
      const int gc = n0 + wn + j * 16 + ccol;
      const float bvv = bias[gc];
#pragma unroll
      for (int r = 0; r < 4; ++r){
        float v = acc[i][j][r] + bvv;
        const int gr = gr0 + r;
        if (isQ) Q[(size_t)gr * 512 + gc] = v;
        else     KV[(size_t)gr * 1024 + (gc - 512)] = f2bf_rtn(v);
      }
    }
  }
}

// ---------- FFN1: A split bf16, B=w1 hi only (x2), out = relu bf16 ----------
__global__ __launch_bounds__(256) void gemm_ffn1(
    const ushort_t* __restrict__ Ah, const ushort_t* __restrict__ Al,
    const ushort_t* __restrict__ Bh, const float* __restrict__ bias,
    ushort_t* __restrict__ Chid){
  __shared__ __align__(16) ushort_t AsH[128 * 32];
  __shared__ __align__(16) ushort_t AsL[128 * 32];
  __shared__ __align__(16) ushort_t BsH[128 * 32];
  int bx, by; xcd_map(bx, by);
  const int tid  = threadIdx.x;
  const int lane = tid & 63;
  const int wv   = tid >> 6;
  const int m0   = by * 128;
  const int n0   = bx * 128;
  const int wm   = (wv & 1) * 64;
  const int wn   = (wv >> 1) * 64;
  const int rowA = tid >> 2;
  const int qe   = (tid & 3) * 8;
  const int lds0 = tid * 8;
  const int lds1 = (tid + 256) * 8;

  f32x4 acc[4][4];
#pragma unroll
  for (int i = 0; i < 4; ++i)
#pragma unroll
    for (int j = 0; j < 4; ++j) acc[i][j] = (f32x4){0.f, 0.f, 0.f, 0.f};

  const int arow = lane & 15;
  const int koff = (lane >> 4) * 8;
  const int K = DD;

  for (int k0 = 0; k0 < K; k0 += 32){
    const size_t ga0 = (size_t)(m0 + rowA) * K + k0 + qe;
    const size_t ga1 = (size_t)(m0 + rowA + 64) * K + k0 + qe;
    const size_t gb0 = (size_t)(n0 + rowA) * K + k0 + qe;
    const size_t gb1 = (size_t)(n0 + rowA + 64) * K + k0 + qe;
    GLD16(Ah + ga0, &AsH[lds0]);  GLD16(Ah + ga1, &AsH[lds1]);
    GLD16(Al + ga0, &AsL[lds0]);  GLD16(Al + ga1, &AsL[lds1]);
    GLD16(Bh + gb0, &BsH[lds0]);  GLD16(Bh + gb1, &BsH[lds1]);
    __syncthreads();

    bf16x8 ah[4], al[4], bh[4];
#pragma unroll
    for (int i = 0; i < 4; ++i){
      ah[i] = *(const bf16x8*)&AsH[(wm + i * 16 + arow) * 32 + koff];
      al[i] = *(const bf16x8*)&AsL[(wm + i * 16 + arow) * 32 + koff];
      bh[i] = *(const bf16x8*)&BsH[(wn + i * 16 + arow) * 32 + koff];
    }
#pragma unroll
    for (int i = 0; i < 4; ++i)
#pragma unroll
      for (int j = 0; j < 4; ++j){
        acc[i][j] = __builtin_amdgcn_mfma_f32_16x16x32_bf16(ah[i], bh[j], acc[i][j], 0, 0, 0);
        acc[i][j] = __builtin_amdgcn_mfma_f32_16x16x32_bf16(al[i], bh[j], acc[i][j], 0, 0, 0);
      }
    __syncthreads();
  }

  const int crow = (lane >> 4) * 4;
  const int ccol = lane & 15;
#pragma unroll
  for (int i = 0; i < 4; ++i){
    const int gr0 = m0 + wm + i * 16 + crow;
#pragma unroll
    for (int j = 0; j < 4; ++j){
      const int gc = n0 + wn + j * 16 + ccol;
      const float bvv = bias[gc];
#pragma unroll
      for (int r = 0; r < 4; ++r){
        float v = fmaxf(acc[i][j][r] + bvv, 0.f);
        Chid[(size_t)(gr0 + r) * DFF + gc] = f2bf_rtn(v);
      }
    }
  }
}

// ---------- FFN2: A single bf16 (hid), B=w2 split (x2), split-K=2 partial fp32 out ----------
__global__ __launch_bounds__(256) void gemm_ffn2(
    const ushort_t* __restrict__ Ahid,
    const ushort_t* __restrict__ Bh, const ushort_t* __restrict__ Bl,
    float* __restrict__ pbuf, size_t pstr){
  __shared__ __align__(16) ushort_t AsH[128 * 32];
  __shared__ __align__(16) ushort_t BsH[128 * 32];
  __shared__ __align__(16) ushort_t BsL[128 * 32];
  int bx, by; xcd_map(bx, by);
  const int tid  = threadIdx.x;
  const int lane = tid & 63;
  const int wv   = tid >> 6;
  const int nblk = bx >> 1;
  const int kq   = bx & 1;
  const int m0   = by * 128;
  const int n0   = nblk * 128;
  const int wm   = (wv & 1) * 64;
  const int wn   = (wv >> 1) * 64;
  const int rowA = tid >> 2;
  const int qe   = (tid & 3) * 8;
  const int lds0 = tid * 8;
  const int lds1 = (tid + 256) * 8;

  f32x4 acc[4][4];
#pragma unroll
  for (int i = 0; i < 4; ++i)
#pragma unroll
    for (int j = 0; j < 4; ++j) acc[i][j] = (f32x4){0.f, 0.f, 0.f, 0.f};

  const int arow = lane & 15;
  const int koff = (lane >> 4) * 8;
  const int K = DFF;
  const int kper = K / 2;
  const int kbeg = kq * kper;

  for (int k0 = kbeg; k0 < kbeg + kper; k0 += 32){
    const size_t ga0 = (size_t)(m0 + rowA) * K + k0 + qe;
    const size_t ga1 = (size_t)(m0 + rowA + 64) * K + k0 + qe;
    const size_t gb0 = (size_t)(n0 + rowA) * K + k0 + qe;
    const size_t gb1 = (size_t)(n0 + rowA + 64) * K + k0 + qe;
    GLD16(Ahid + ga0, &AsH[lds0]);  GLD16(Ahid + ga1, &AsH[lds1]);
    GLD16(Bh + gb0, &BsH[lds0]);    GLD16(Bh + gb1, &BsH[lds1]);
    GLD16(Bl + gb0, &BsL[lds0]);    GLD16(Bl + gb1, &BsL[lds1]);
    __syncthreads();

    bf16x8 ah[4], bh[4], bl[4];
#pragma unroll
    for (int i = 0; i < 4; ++i){
      ah[i] = *(const bf16x8*)&AsH[(wm + i * 16 + arow) * 32 + koff];
      bh[i] = *(const bf16x8*)&BsH[(wn + i * 16 + arow) * 32 + koff];
      bl[i] = *(const bf16x8*)&BsL[(wn + i * 16 + arow) * 32 + koff];
    }
#pragma unroll
    for (int i = 0; i < 4; ++i)
#pragma unroll
      for (int j = 0; j < 4; ++j){
        acc[i][j] = __builtin_amdgcn_mfma_f32_16x16x32_bf16(ah[i], bh[j], acc[i][j], 0, 0, 0);
        acc[i][j] = __builtin_amdgcn_mfma_f32_16x16x32_bf16(ah[i], bl[j], acc[i][j], 0, 0, 0);
      }
    __syncthreads();
  }

  const int crow = (lane >> 4) * 4;
  const int ccol = lane & 15;
#pragma unroll
  for (int i = 0; i < 4; ++i){
    const int gr0 = m0 + wm + i * 16 + crow;
#pragma unroll
    for (int j = 0; j < 4; ++j){
      const int gc = n0 + wn + j * 16 + ccol;
#pragma unroll
      for (int r = 0; r < 4; ++r)
        pbuf[(size_t)kq * pstr + (size_t)(gr0 + r) * DD + gc] = acc[i][j][r];
    }
  }
}

// ---------- qs scoring, one quarter (standalone, high occupancy) ----------
__global__ __launch_bounds__(256) void qs_kernel(const float* __restrict__ qbuf, float* __restrict__ qsb){
  int tid = threadIdx.x;
  int lane = tid & 63;
  int wv = tid >> 6;
  int rid = blockIdx.x * 4 + wv;
  int bloc = rid >> 15;
  int hh = (rid >> 12) & 7;
  int l  = rid & (LL - 1);
  float qv = qbuf[((size_t)bloc * LL + l) * DD + hh * DKK + lane];
  float l2 = sqrtf(wsum(qv * qv));
  float mx = qv;
#pragma unroll
  for (int o = 32; o > 0; o >>= 1) mx = fmaxf(mx, __shfl_xor(mx, o));
  float e  = expf(qv - mx);
  float se = wsum(e);
  float p  = e / se;
  float ent = -wsum(p * logf(p + 1e-9f));
  float mu  = wsum(qv) * (1.0f / 64.0f);
  float dv  = qv - mu;
  float var = wsum(dv * dv) * (1.0f / 63.0f);
  float val = 0.5f * l2 + 0.3f * ent + 0.2f * var;
  if (lane == 0) qsb[(size_t)(bloc * HH + hh) * LL + l] = val;
}

// ---------- selection (incremental top-k) + fused slot allocation ----------
__global__ __launch_bounds__(256) void select_kernel(const float* __restrict__ qsb,
    int* __restrict__ topidx, int* __restrict__ ufac,
    int* __restrict__ slotmap, int* __restrict__ scount, int qtr){
  __shared__ float vals[LL];
  __shared__ float bv[256];
  __shared__ int   bi[256];
  __shared__ int   widx_s;
  __shared__ int   swin[UMAX];
  __shared__ double r1[256], r2[256];
  const int bloc = blockIdx.y;
  const int b = qtr * NB + bloc;
  int tid = threadIdx.x;
  if (blockIdx.x == 8){
    const float* row = qsb + (size_t)bloc * HH * LL;
    double s = 0.0, s2 = 0.0;
    for (int l = tid; l < LL; l += 256){ double v = row[l]; s += v; s2 += v * v; }
    r1[tid] = s; r2[tid] = s2; __syncthreads();
    for (int st = 128; st; st >>= 1){
      if (tid < st){ r1[tid] += r1[tid+st]; r2[tid] += r2[tid+st]; }
      __syncthreads();
    }
    if (tid == 0){
      double mean = r1[0] / (double)LL;
      double var  = (r2[0] - (double)LL * mean * mean) / (double)(LL - 1);
      if (var < 0.0) var = 0.0;
      double f = rint(sqrt(var) / (mean + 1e-6) * 10.0);
      if (f < 3.0) f = 3.0;
      if (f > 10.0) f = 10.0;
      ufac[b] = (int)f;
    }
    return;
  }
  int hh = blockIdx.x;
  const float* row = qsb + ((size_t)bloc * HH + hh) * LL;
  for (int l = tid; l < LL; l += 256) vals[l] = row[l];
  __syncthreads();
  float lmax = -INFINITY; int lidx = 0;
  for (int l = tid; l < LL; l += 256){
    float v = vals[l];
    if (v > lmax){ lmax = v; lidx = l; }
  }
  for (int it = 0; it < UMAX; ++it){
    bv[tid] = lmax; bi[tid] = lidx;
    __syncthreads();
    for (int st = 128; st; st >>= 1){
      if (tid < st){
        if (bv[tid+st] > bv[tid] || (bv[tid+st] == bv[tid] && bi[tid+st] < bi[tid])){
          bv[tid] = bv[tid+st]; bi[tid] = bi[tid+st];
        }
      }
      __syncthreads();
    }
    if (tid == 0){ topidx[(b * HH + hh) * UMAX + it] = bi[0]; widx_s = bi[0]; swin[it] = bi[0]; }
    __syncthreads();
    const int w = widx_s;
    if ((w & 255) == tid){
      vals[w] = -INFINITY;
      lmax = -INFINITY; lidx = 0;
      for (int l = tid; l < LL; l += 256){
        float v = vals[l];
        if (v > lmax){ lmax = v; lidx = l; }
      }
    }
    __syncthreads();
  }
  if (tid < UMAX){
    int qpos = swin[tid];
    int* cell = &slotmap[b * LL + qpos];
    int old = atomicCAS(cell, -1, -2);
    if (old == -1){
      int s = atomicAdd(&scount[b], 1);
      atomicExch(cell, s);
    }
  }
}

// ---------- reset: slotmap=-1, scount=0, adelta=0 ----------
__global__ void reset_kernel(int* __restrict__ slotmap, int* __restrict__ scount,
    float* __restrict__ adelta){
  size_t i = (size_t)blockIdx.x * 256 + threadIdx.x;
  size_t stride = (size_t)gridDim.x * 256;
  for (size_t k = i; k < (size_t)BB * LL; k += stride) slotmap[k] = -1;
  for (size_t k = i; k < (size_t)BB * MAXSLOT * DD; k += stride) adelta[k] = 0.f;
  if (i < BB) scount[i] = 0;
}

// ---------- attention pass 1: early-exit, K/V in regs once, loop over ranks ----------
__global__ __launch_bounds__(256) void attn_p1_kernel(const float* __restrict__ qbuf,
    const ushort_t* __restrict__ kvbuf,
    const int* __restrict__ topidx, const int* __restrict__ ufac,
    float* __restrict__ part, int qtr, int lmin){
  const int bloc = blockIdx.z;
  const int b = qtr * NB + bloc;
  const int hh = blockIdx.y;
  const int u = ufac[b];
  // block-uniform early-exit: skip 32KB K/V load when no rank qualifies (tail layer)
  bool any = false;
  for (int rank = 0; rank < u; ++rank)
    if (topidx[(b * HH + hh) * UMAX + rank] >= lmin){ any = true; break; }
  if (!any) return;

  const int tid = threadIdx.x, lane = tid & 63, wv = tid >> 6;
  const int base = blockIdx.x * LCHUNK + wv * 32;

  const ushort_t* Kp = kvbuf + (size_t)bloc * LL * 1024 + hh * DKK + lane;
  const ushort_t* Vp = Kp + 512;
  float kreg[32], vreg[32];
#pragma unroll
  for (int i = 0; i < 32; ++i){
    kreg[i] = bf2f(Kp[(size_t)(base + i) * 1024]);
    vreg[i] = bf2f(Vp[(size_t)(base + i) * 1024]);
  }

  __shared__ float wm4[4], ws4[4];
  __shared__ float pvs[4][DKK];

  for (int rank = 0; rank < u; ++rank){
    const int qpos = topidx[(b * HH + hh) * UMAX + rank];
    if (qpos < lmin) continue;
    const float qv = qbuf[((size_t)bloc * LL + qpos) * DD + hh * DKK + lane];

    float sc[32];
    float mloc = -INFINITY;
#pragma unroll
    for (int i = 0; i < 32; ++i){
      float s = wsum(qv * kreg[i]) * 0.125f;
      sc[i] = s;
      mloc = fmaxf(mloc, s);
    }
    if (lane == 0) wm4[wv] = mloc;
    __syncthreads();
    const float M4 = fmaxf(fmaxf(wm4[0], wm4[1]), fmaxf(wm4[2], wm4[3]));

    float ssum = 0.f;
#pragma unroll
    for (int i = 0; i < 32; ++i){ float e = expf(sc[i] - M4); sc[i] = e; ssum += e; }

    float pv = 0.f;
#pragma unroll
    for (int i = 0; i < 32; ++i) pv += sc[i] * vreg[i];

    pvs[wv][lane] = pv;
    if (lane == 0) ws4[wv] = ssum;
    __syncthreads();
    if (wv == 0){
      const int rowid = hh * UMAX + rank;
      float* rec = part + (size_t)((bloc * HH * UMAX + rowid) * NSPLIT + blockIdx.x) * PSTRIDE;
      rec[lane] = pvs[0][lane] + pvs[1][lane] + pvs[2][lane] + pvs[3][lane];
      if (lane == 0){ rec[64] = M4; rec[65] = ws4[0] + ws4[1] + ws4[2] + ws4[3]; }
    }
    __syncthreads();
  }
}

// ---------- attention pass 2: combine + wo projection -> adelta ----------
__global__ __launch_bounds__(256) void attn_p2_kernel(const float* __restrict__ part,
    const float* __restrict__ wo, const int* __restrict__ topidx, const int* __restrict__ ufac,
    const int* __restrict__ slotmap, float* __restrict__ adelta, int qtr, int lmin){
  const int bloc = blockIdx.y;
  const int b = qtr * NB + bloc;
  const int rowid = blockIdx.x;
  const int hh = rowid / UMAX, rank = rowid % UMAX;
  if (rank >= ufac[b]) return;
  const int qpos = topidx[(b * HH + hh) * UMAX + rank];
  if (qpos < lmin) return;
  const int slot = slotmap[b * LL + qpos];

  const int tid = threadIdx.x;
  const float* pbase = part + (size_t)(bloc * HH * UMAX + rowid) * NSPLIT * PSTRIDE;
  __shared__ float pm[NSPLIT], ps[NSPLIT];
  __shared__ float orow[DKK];
  if (tid < NSPLIT){
    pm[tid] = pbase[(size_t)tid * PSTRIDE + 64];
    ps[tid] = pbase[(size_t)tid * PSTRIDE + 65];
  }
  __syncthreads();
  float M = -INFINITY;
#pragma unroll
  for (int i = 0; i < NSPLIT; ++i) M = fmaxf(M, pm[i]);
  float S = 0.f;
#pragma unroll
  for (int i = 0; i < NSPLIT; ++i) S += ps[i] * expf(pm[i] - M);
  if (tid < DKK){
    float acc = 0.f;
#pragma unroll
    for (int i = 0; i < NSPLIT; ++i)
      acc += pbase[(size_t)i * PSTRIDE + tid] * expf(pm[i] - M);
    orow[tid] = acc / S;
  }
  __syncthreads();
  float* drow = adelta + ((size_t)b * MAXSLOT + slot) * DD;
  for (int j = tid; j < DD; j += 256){
    float a = 0.f;
#pragma unroll
    for (int dd = 0; dd < DKK; ++dd) a += orow[dd] * wo[(size_t)(hh * DKK + dd) * DD + j];
    atomicAdd(&drow[j], a);
  }
}

// ---------- LN1: one-pass sum/sumsq, wave reduce ----------
template<bool TAIL>
__global__ __launch_bounds__(256) void ln1_kernel(
    const ushort_t* __restrict__ hh_, const ushort_t* __restrict__ hl_,
    const float* __restrict__ bo,
    const int* __restrict__ slotmap, const float* __restrict__ adelta,
    ushort_t* __restrict__ oh, ushort_t* __restrict__ ol,
    const float* __restrict__ g, const float* __restrict__ bb){
  __shared__ float ss[4], qq[4];
  int r = blockIdx.x, tid = threadIdx.x;
  const int lane = tid & 63, wv = tid >> 6;
  int b, l;
  if (TAIL){ b = r / OUTLEN; l = TAIL0 + (r % OUTLEN); }
  else     { b = r >> 12;    l = r & (LL - 1); }
  const size_t gi = ((size_t)b * LL + l) * DD;
  const int j0 = 2 * tid;
  const uint_t hp = *(const uint_t*)(hh_ + gi + j0);
  const uint_t lp = *(const uint_t*)(hl_ + gi + j0);
  const float2 bo2 = *(const float2*)&bo[j0];
  float v0 = bf2f((ushort_t)(hp & 0xFFFF)) + bf2f((ushort_t)(lp & 0xFFFF)) + bo2.x;
  float v1 = bf2f((ushort_t)(hp >> 16))    + bf2f((ushort_t)(lp >> 16))    + bo2.y;
  int s = slotmap[b * LL + l];
  if (s >= 0){
    const float2 dr = *(const float2*)&adelta[((size_t)b * MAXSLOT + s) * DD + j0];
    v0 += dr.x; v1 += dr.y;
  }
  float sm = v0 + v1, qm = v0 * v0 + v1 * v1;
#pragma unroll
  for (int o2 = 32; o2 > 0; o2 >>= 1){ sm += __shfl_xor(sm, o2); qm += __shfl_xor(qm, o2); }
  if (lane == 0){ ss[wv] = sm; qq[wv] = qm; }
  __syncthreads();
  const float S = ss[0] + ss[1] + ss[2] + ss[3];
  const float Qv = qq[0] + qq[1] + qq[2] + qq[3];
  const float mu = S * (1.0f / DD);
  float var = Qv * (1.0f / DD) - mu * mu;
  const float rstd = rsqrtf(var + 1e-5f);
  const float2 g2 = *(const float2*)&g[j0];
  const float2 bb2 = *(const float2*)&bb[j0];
  float o0 = (v0 - mu) * rstd * g2.x + bb2.x;
  float o1 = (v1 - mu) * rstd * g2.y + bb2.y;
  const size_t oo = TAIL ? (size_t)r * DD : gi;
  ushort_t h0, l0, h1, l1;
  split2(o0, h0, l0); split2(o1, h1, l1);
  *(uint_t*)(oh + oo + j0) = (uint_t)h0 | ((uint_t)h1 << 16);
  *(uint_t*)(ol + oo + j0) = (uint_t)l0 | ((uint_t)l1 << 16);
}

// ---------- LN2: one-pass, two split-K partials ----------
template<bool TAIL>
__global__ __launch_bounds__(256) void ln2_kernel(
    const ushort_t* __restrict__ ih, const ushort_t* __restrict__ il,
    const float* __restrict__ pbuf, size_t pstr, const float* __restrict__ b2,
    ushort_t* __restrict__ oh, ushort_t* __restrict__ ol, float* __restrict__ ofp,
    const float* __restrict__ g, const float* __restrict__ bb, size_t rowoff){
  __shared__ float ss[4], qq[4];
  int r = blockIdx.x, tid = threadIdx.x;
  const int lane = tid & 63, wv = tid >> 6;
  const size_t gi = (rowoff + r) * DD;
  const size_t pi = (size_t)r * DD;
  const int j0 = 2 * tid;
  const uint_t hp = *(const uint_t*)(ih + gi + j0);
  const uint_t lp = *(const uint_t*)(il + gi + j0);
  const float2 p0 = *(const float2*)&pbuf[pi + j0];
  const float2 p1 = *(const float2*)&pbuf[pstr + pi + j0];
  const float2 b22 = *(const float2*)&b2[j0];
  float v0 = bf2f((ushort_t)(hp & 0xFFFF)) + bf2f((ushort_t)(lp & 0xFFFF)) + p0.x + p1.x + b22.x;
  float v1 = bf2f((ushort_t)(hp >> 16))    + bf2f((ushort_t)(lp >> 16))    + p0.y + p1.y + b22.y;
  float sm = v0 + v1, qm = v0 * v0 + v1 * v1;
#pragma unroll
  for (int o2 = 32; o2 > 0; o2 >>= 1){ sm += __shfl_xor(sm, o2); qm += __shfl_xor(qm, o2); }
  if (lane == 0){ ss[wv] = sm; qq[wv] = qm; }
  __syncthreads();
  const float S = ss[0] + ss[1] + ss[2] + ss[3];
  const float Qv = qq[0] + qq[1] + qq[2] + qq[3];
  const float mu = S * (1.0f / DD);
  float var = Qv * (1.0f / DD) - mu * mu;
  const float rstd = rsqrtf(var + 1e-5f);
  const float2 g2 = *(const float2*)&g[j0];
  const float2 bb2 = *(const float2*)&bb[j0];
  float o0 = (v0 - mu) * rstd * g2.x + bb2.x;
  float o1 = (v1 - mu) * rstd * g2.y + bb2.y;
  if (TAIL){
    ofp[pi + j0] = o0; ofp[pi + j0 + 1] = o1;
  } else {
    ushort_t h0, l0, h1, l1;
    split2(o0, h0, l0); split2(o1, h1, l1);
    *(uint_t*)(oh + gi + j0) = (uint_t)h0 | ((uint_t)h1 << 16);
    *(uint_t*)(ol + gi + j0) = (uint_t)l0 | ((uint_t)l1 << 16);
  }
}

// ---------- final ----------
__global__ __launch_bounds__(64) void pred_kernel(const float* __restrict__ ht,
    const float* __restrict__ wout, const float* __restrict__ bout, float* __restrict__ out){
  int r = blockIdx.x, lane = threadIdx.x;
  float acc = 0.f;
  for (int dd = lane; dd < DD; dd += 64) acc += ht[(size_t)r * DD + dd] * wout[dd];
  acc = wsum(acc);
  if (lane == 0) out[r] = acc + bout[0];
}

extern "C" void kernel_launch(void* const* d_in, const int* in_sizes, int n_in,
                              void* d_out, int out_size, void* d_ws, size_t ws_size,
                              hipStream_t stream){
  const float* x    = (const float*)d_in[0];
  const float* wemb = (const float*)d_in[1];
  const float* bemb = (const float*)d_in[2];
  const float* wq   = (const float*)d_in[3];
  const float* bq   = (const float*)d_in[4];
  const float* wk   = (const float*)d_in[5];
  const float* bk   = (const float*)d_in[6];
  const float* wv   = (const float*)d_in[7];
  const float* bvv  = (const float*)d_in[8];
  const float* wo   = (const float*)d_in[9];
  const float* bo   = (const float*)d_in[10];
  const float* w1   = (const float*)d_in[11];
  const float* b1   = (const float*)d_in[12];
  const float* w2   = (const float*)d_in[13];
  const float* b2   = (const float*)d_in[14];
  const float* g1   = (const float*)d_in[15];
  const float* be1  = (const float*)d_in[16];
  const float* g2   = (const float*)d_in[17];
  const float* be2  = (const float*)d_in[18];
  const float* wout = (const float*)d_in[19];
  const float* bout = (const float*)d_in[20];
  float* out = (float*)d_out;
  char* wsb  = (char*)d_ws;

  const size_t MiB = 1024 * 1024;
  const size_t NE  = (size_t)BB * LL * DD;   // 33.5M elems

  size_t o = 0;
  ushort_t* hh    = (ushort_t*)(wsb + o); o += NE * 2;          // 64 MiB
  ushort_t* hl    = (ushort_t*)(wsb + o); o += NE * 2;          // 64 MiB
  char*     arena = wsb + o;              o += 64 * MiB;        // shared arena
  // QKV phase:
  float*    qbuf  = (float*)arena;                              // 32 MiB
  ushort_t* kvbuf = (ushort_t*)(arena + 32 * MiB);              // 32 MiB
  // FFN phase (overlay):
  ushort_t* hid   = (ushort_t*)arena;                           // CH*DFF*2 = 32 MiB
  float*    pbuf  = (float*)(arena + 32 * MiB);                 // 2*CH*512*4 = 32 MiB
  // FFN tail overlay
  ushort_t* hidt  = (ushort_t*)arena;                           // 6 MiB
  float*    pbuft = (float*)(arena + 32 * MiB);                 // 6 MiB
  ushort_t* asht  = (ushort_t*)(arena + 48 * MiB);              // 1.5 MiB
  ushort_t* aslt  = (ushort_t*)(arena + 50 * MiB);              // 1.5 MiB
  // weights + small:
  ushort_t* wtqkvh = (ushort_t*)(wsb + o); o += (size_t)QKVN * DD * 2;
  ushort_t* wtqkvl = (ushort_t*)(wsb + o); o += (size_t)QKVN * DD * 2;
  ushort_t* w1th   = (ushort_t*)(wsb + o); o += (size_t)DFF * DD * 2;
  ushort_t* w2th   = (ushort_t*)(wsb + o); o += (size_t)DD * DFF * 2;
  ushort_t* w2tl   = (ushort_t*)(wsb + o); o += (size_t)DD * DFF * 2;
  ushort_t* w1tl   = (ushort_t*)(wsb + o); o += (size_t)DFF * DD * 2;  // scratch
  float*    bqkv   = (float*)(wsb + o);  o += QKVN * 4;
  float*    qsb    = (float*)(wsb + o);  o += (size_t)NB * HH * LL * 4;
  float*    part   = (float*)(wsb + o);  o += (size_t)NB * HH * UMAX * NSPLIT * PSTRIDE * 4;
  float*    adelta = (float*)(wsb + o);  o += (size_t)BB * MAXSLOT * DD * 4;
  float*    htail  = (float*)(wsb + o);  o += (size_t)NTAIL * DD * 4;
  int*      slotmap= (int*)(wsb + o);    o += (size_t)BB * LL * 4;
  int*      scount = (int*)(wsb + o);    o += BB * 4;
  int*      topidx = (int*)(wsb + o);    o += (size_t)BB * HH * UMAX * 4;
  int*      ufac   = (int*)(wsb + o);    o += 64;
  // total ~215 MiB (<= 234 proven-safe)

  wqkv_prep_kernel<<<dim3(QKVN/32, DD/32), 256, 0, stream>>>(wq, wk, wv, wtqkvh, wtqkvl);
  bqkv_prep_kernel<<<(QKVN + 255)/256, 256, 0, stream>>>(bq, bk, bvv, bqkv);
  wsplit_t_kernel<<<dim3(DFF/32, DD/32), 256, 0, stream>>>(w1, w1th, w1tl, DD, DFF);
  wsplit_t_kernel<<<dim3(DD/32, DFF/32), 256, 0, stream>>>(w2, w2th, w2tl, DFF, DD);

  embed_kernel<<<(BB * LL) / EROWS, 256, 0, stream>>>(x, wemb, bemb, hh, hl);

  for (int layer = 0; layer < 2; ++layer){
    const bool tail = (layer == 1);
    const int lmin = tail ? TAIL0 : 0;

    reset_kernel<<<1024, 256, 0, stream>>>(slotmap, scount, adelta);

    for (int qtr = 0; qtr < BB / NB; ++qtr){
      const size_t hoff = (size_t)qtr * QM * DD;
      gemm_qkv<<<dim3(QKVN/128, QM/128), 256, 0, stream>>>(
          hh + hoff, hl + hoff, wtqkvh, wtqkvl, bqkv, qbuf, kvbuf);
      qs_kernel<<<(NB*HH*LL)/4, 256, 0, stream>>>(qbuf, qsb);
      select_kernel<<<dim3(9, NB), 256, 0, stream>>>(qsb, topidx, ufac, slotmap, scount, qtr);
      attn_p1_kernel<<<dim3(NSPLIT, HH, NB), 256, 0, stream>>>(
          qbuf, kvbuf, topidx, ufac, part, qtr, lmin);
      attn_p2_kernel<<<dim3(HH*UMAX, NB), 256, 0, stream>>>(
          part, wo, topidx, ufac, slotmap, adelta, qtr, lmin);
    }

    if (!tail){
      ln1_kernel<false><<<BB*LL, 256, 0, stream>>>(hh, hl, bo, slotmap, adelta, hh, hl, g1, be1);
      for (int c = 0; c < (BB*LL)/CH; ++c){
        const size_t roff = (size_t)c * CH;
        gemm_ffn1<<<dim3(DFF/128, CH/128), 256, 0, stream>>>(
            hh + roff * DD, hl + roff * DD, w1th, b1, hid);
        gemm_ffn2<<<dim3(8, CH/128), 256, 0, stream>>>(hid, w2th, w2tl, pbuf, (size_t)CH * DD);
        ln2_kernel<false><<<CH, 256, 0, stream>>>(
            hh, hl, pbuf, (size_t)CH * DD, b2, hh, hl, nullptr, g2, be2, roff);
      }
    } else {
      ln1_kernel<true><<<NTAIL, 256, 0, stream>>>(hh, hl, bo, slotmap, adelta, asht, aslt, g1, be1);
      gemm_ffn1<<<dim3(DFF/128, NTAIL/128), 256, 0, stream>>>(asht, aslt, w1th, b1, hidt);
      gemm_ffn2<<<dim3(8, NTAIL/128), 256, 0, stream>>>(hidt, w2th, w2tl, pbuft, (size_t)NTAIL * DD);
      ln2_kernel<true><<<NTAIL, 256, 0, stream>>>(
          asht, aslt, pbuft, (size_t)NTAIL * DD, b2, nullptr, nullptr, htail, g2, be2, 0);
      pred_kernel<<<NTAIL, 64, 0, stream>>>(htail, wout, bout, out);
    }
  }
  (void)in_sizes; (void)n_in; (void)out_size; (void)ws_size;
}